// Round 11
// baseline (1652.589 us; speedup 1.0000x reference)
//
#include <hip/hip_runtime.h>
#include <hip/hip_bf16.h>
#include <math.h>

typedef __hip_bfloat16 bf16;
typedef __attribute__((ext_vector_type(8))) short short8;
typedef __attribute__((ext_vector_type(4))) float floatx4;
typedef __attribute__((ext_vector_type(4))) unsigned short ushort4v;

#define LRELU(v) ((v) < 0.f ? 0.2f * (v) : (v))

__device__ __forceinline__ float b2f(bf16 x) { return __bfloat162float(x); }
__device__ __forceinline__ int img_group(int n) { return n < 75 ? 0 : (n < 100 ? 1 : 2); }

// ------------------------------------------------------- dtype detection ----
__global__ __launch_bounds__(64) void detect_kernel(
    const void* in1, const void* in2, const void* in3,
    const void* w1, const void* w2, const void* w3, const void* w4,
    const void* g1, const void* g2, const void* g3, const void* g4,
    int* __restrict__ flags)
{
  int t = threadIdx.x;
  if (t >= 11) return;
  const void* p = nullptr; int nh = 384, isg = 0;
  switch (t) {
    case 0: p = in1; break;  case 1: p = in2; break;  case 2: p = in3; break;
    case 3: p = w1;  break;  case 4: p = w2;  break;  case 5: p = w3;  break;
    case 6: p = w4;  break;
    case 7: p = g1; nh = 64; isg = 1; break;
    case 8: p = g2; nh = 64; isg = 1; break;
    case 9: p = g3; nh = 64; isg = 1; break;
    case 10: p = g4; nh = 64; isg = 1; break;
  }
  const unsigned short* h = (const unsigned short*)p;
  int cnt = 0;
  for (int i = 0; i < nh; ++i) {
    unsigned short v = h[i];
    if (isg) {
      if (v == 0) ++cnt;
    } else {
      int e = (v >> 7) & 0xFF;
      if (e >= 160 || (e > 0 && e <= 80)) ++cnt;
    }
  }
  flags[t] = isg ? (cnt >= 16) : (cnt >= 48);
}

// canonicalize images -> PADDED bf16 [164][3][86][86]; borders pre-zeroed
__global__ __launch_bounds__(256) void cvt_images_kernel(
    const void* s1, const void* s2, const void* s3,
    const int* __restrict__ flags, bf16* __restrict__ dst)
{
  int k = blockIdx.x * 256 + threadIdx.x;
  if (k >= 164 * 21168) return;
  const void* src; int idx, f;
  if (k < 75 * 21168)       { src = s1; idx = k;               f = flags[0]; }
  else if (k < 100 * 21168) { src = s2; idx = k - 75 * 21168;  f = flags[1]; }
  else                      { src = s3; idx = k - 100 * 21168; f = flags[2]; }
  bf16 v = f ? __float2bfloat16(((const float*)src)[idx]) : ((const bf16*)src)[idx];
  int n = k / 21168, r = k % 21168;
  int ci = r / 7056, pix = r % 7056;
  int y = pix / 84, x = pix % 84;
  dst[((size_t)(n * 3 + ci) * 86 + y + 1) * 86 + x + 1] = v;
}

__global__ __launch_bounds__(256) void cvt_param_kernel(
    const void* src, float* __restrict__ dst, int n,
    const int* __restrict__ flags, int fidx)
{
  int i = blockIdx.x * 256 + threadIdx.x;
  if (i >= n) return;
  int isf32 = (fidx >= 0) ? flags[fidx] : 0;
  dst[i] = isf32 ? ((const float*)src)[i] : b2f(((const bf16*)src)[i]);
}

// repack conv weights f32 [co][ci][3][3] -> bf16 [tap][co][ci]
__global__ __launch_bounds__(256) void pack_w_kernel(
    const float* __restrict__ w, bf16* __restrict__ wp)
{
  int i = blockIdx.x * 256 + threadIdx.x;
  if (i >= 36864) return;
  int co = i / 576, ci = (i / 9) % 64, tap = i % 9;
  wp[((size_t)tap * 64 + co) * 64 + ci] = __float2bfloat16(w[i]);
}

// pack conv1 weights f32 [64][27] -> bf16 [64][32] (zero-padded K)
__global__ __launch_bounds__(256) void pack_w1_kernel(
    const float* __restrict__ w, bf16* __restrict__ wp)
{
  int i = blockIdx.x * 256 + threadIdx.x;
  if (i >= 2048) return;
  int co = i >> 5, k = i & 31;
  wp[i] = __float2bfloat16(k < 27 ? w[co * 27 + k] : 0.f);
}

// ---------------------------------------------------------------- prep ------
__global__ __launch_bounds__(256) void prep_kernel(
    float* __restrict__ part, float* __restrict__ uscore, float* __restrict__ qscore)
{
  int i = blockIdx.x * 256 + threadIdx.x;
  if (i < 164 * 128) part[i] = 0.f;
  if (i < 320) uscore[i] = 0.f;
  if (i < 375) qscore[i] = 0.f;
}

// --------------------------------------------------- conv1 via MFMA (K=27) --
__global__ __launch_bounds__(256) void conv1_stats_mfma(
    const bf16* __restrict__ imgp, const bf16* __restrict__ w1p,
    float* __restrict__ part)
{
  __shared__ float sacc[128];
  int n = blockIdx.x, tile = blockIdx.y;
  int lane = threadIdx.x & 63, wave = threadIdx.x >> 6;
  int q = lane >> 4, c = lane & 15;
  int p = tile * 64 + wave * 16 + c;
  bool valid = p < 7056;
  int pc = valid ? p : 0;
  int y = pc / 84, x = pc % 84;
  const short* ib = (const short*)(imgp + (size_t)n * 3 * 86 * 86);
  short bs[8];
  #pragma unroll
  for (int j = 0; j < 8; ++j) {
    int k = q * 8 + j;
    int ci = k / 9, tap = k - ci * 9;
    int dy = tap / 3, dx = tap - dy * 3;
    bs[j] = (k < 27 && valid) ? ib[(ci * 86 + y + dy) * 86 + x + dx] : (short)0;
  }
  short8 B = {bs[0], bs[1], bs[2], bs[3], bs[4], bs[5], bs[6], bs[7]};
  float s[16], sq[16];
  #pragma unroll
  for (int t = 0; t < 4; ++t) {
    const short* ap = (const short*)w1p + (t * 16 + c) * 32 + q * 8;
    short8 A = *(const short8*)ap;
    floatx4 acc = {0.f, 0.f, 0.f, 0.f};
    acc = __builtin_amdgcn_mfma_f32_16x16x32_bf16(A, B, acc, 0, 0, 0);
    #pragma unroll
    for (int r = 0; r < 4; ++r) { s[t * 4 + r] = acc[r]; sq[t * 4 + r] = acc[r] * acc[r]; }
  }
  #pragma unroll
  for (int off = 1; off < 16; off <<= 1)
    #pragma unroll
    for (int i = 0; i < 16; ++i) {
      s[i]  += __shfl_xor(s[i], off);
      sq[i] += __shfl_xor(sq[i], off);
    }
  if (threadIdx.x < 128) sacc[threadIdx.x] = 0.f;
  __syncthreads();
  if (c == 0) {
    #pragma unroll
    for (int t = 0; t < 4; ++t)
      #pragma unroll
      for (int r = 0; r < 4; ++r) {
        int co = t * 16 + q * 4 + r;
        atomicAdd(&sacc[co], s[t * 4 + r]);
        atomicAdd(&sacc[64 + co], sq[t * 4 + r]);
      }
  }
  __syncthreads();
  if (threadIdx.x < 128) atomicAdd(&part[n * 128 + threadIdx.x], sacc[threadIdx.x]);
}

__global__ __launch_bounds__(256) void finalize1b_kernel(
    const float* __restrict__ part, const float* __restrict__ gam, const float* __restrict__ bet,
    float* __restrict__ scl, float* __restrict__ sht)
{
  int t = threadIdx.x;
  if (t >= 192) return;
  int g = t / 64, c = t % 64;
  const int starts[3] = {0, 75, 100}, cnts[3] = {75, 25, 64};
  float S = 0.f, Q = 0.f;
  for (int im = starts[g]; im < starts[g] + cnts[g]; ++im) {
    S += part[im * 128 + c];
    Q += part[im * 128 + 64 + c];
  }
  float N = (float)cnts[g] * 7056.f;
  float mean = S / N;
  float var = fmaxf(Q / N - mean * mean, 0.f);
  float rstd = rsqrtf(var + 1e-5f);
  float sc = gam[c] * rstd;
  scl[t] = sc;
  sht[t] = bet[c] - mean * sc;
}

// conv1 + bn + lrelu + 2x2 maxpool, writing DIRECTLY to transposed-padded p1t
__global__ __launch_bounds__(256) void conv1_pool_mfma(
    const bf16* __restrict__ imgp, const bf16* __restrict__ w1p,
    const float* __restrict__ scl, const float* __restrict__ sht,
    bf16* __restrict__ p1t)   // [164][1936][64]
{
  int n = blockIdx.x, tile = blockIdx.y;
  int lane = threadIdx.x & 63, wave = threadIdx.x >> 6;
  int q = lane >> 4, c = lane & 15;
  int pp = tile * 64 + wave * 16 + c;
  bool valid = pp < 1764;
  int pc = valid ? pp : 0;
  int py = pc / 42, px = pc % 42;
  int g = img_group(n);
  const short* ib = (const short*)(imgp + (size_t)n * 3 * 86 * 86);
  short8 B[4];
  #pragma unroll
  for (int quad = 0; quad < 4; ++quad) {
    int y = 2 * py + (quad >> 1), x = 2 * px + (quad & 1);
    short bs[8];
    #pragma unroll
    for (int j = 0; j < 8; ++j) {
      int k = q * 8 + j;
      int ci = k / 9, tap = k - ci * 9;
      int dy = tap / 3, dx = tap - dy * 3;
      bs[j] = (k < 27) ? ib[(ci * 86 + y + dy) * 86 + x + dx] : (short)0;
    }
    B[quad] = (short8){bs[0], bs[1], bs[2], bs[3], bs[4], bs[5], bs[6], bs[7]};
  }
  bf16* ob = p1t + ((size_t)n * 1936 + (py + 1) * 44 + px + 1) * 64;
  #pragma unroll
  for (int t = 0; t < 4; ++t) {
    const short* ap = (const short*)w1p + (t * 16 + c) * 32 + q * 8;
    short8 A = *(const short8*)ap;
    floatx4 a0 = {0.f,0.f,0.f,0.f}, a1 = a0, a2 = a0, a3 = a0;
    a0 = __builtin_amdgcn_mfma_f32_16x16x32_bf16(A, B[0], a0, 0, 0, 0);
    a1 = __builtin_amdgcn_mfma_f32_16x16x32_bf16(A, B[1], a1, 0, 0, 0);
    a2 = __builtin_amdgcn_mfma_f32_16x16x32_bf16(A, B[2], a2, 0, 0, 0);
    a3 = __builtin_amdgcn_mfma_f32_16x16x32_bf16(A, B[3], a3, 0, 0, 0);
    if (valid) {
      ushort4v st;
      #pragma unroll
      for (int r = 0; r < 4; ++r) {
        int co = t * 16 + q * 4 + r;
        float sc_ = scl[g * 64 + co], sh_ = sht[g * 64 + co];
        float v0 = a0[r] * sc_ + sh_; v0 = LRELU(v0);
        float v1 = a1[r] * sc_ + sh_; v1 = LRELU(v1);
        float v2 = a2[r] * sc_ + sh_; v2 = LRELU(v2);
        float v3 = a3[r] * sc_ + sh_; v3 = LRELU(v3);
        float best = fmaxf(fmaxf(v0, v1), fmaxf(v2, v3));
        bf16 bv = __float2bfloat16(best);
        st[r] = *(unsigned short*)&bv;
      }
      *(ushort4v*)(ob + t * 16 + q * 4) = st;
    }
  }
}

// ------------------------------------------- transpose + zero-pad helper ---
__global__ __launch_bounds__(256) void tpad_kernel(
    const bf16* __restrict__ in, bf16* __restrict__ outp,
    int HW, int W, int PW, int PHPW)
{
  __shared__ bf16 tile[64][65];
  int n = blockIdx.x, t0 = blockIdx.y * 64;
  for (int idx = threadIdx.x; idx < 4096; idx += 256) {
    int ci = idx >> 6, pix = idx & 63;
    int p = t0 + pix;
    tile[pix][ci] = (p < HW) ? in[((size_t)n * 64 + ci) * HW + p] : __float2bfloat16(0.f);
  }
  __syncthreads();
  for (int idx = threadIdx.x; idx < 4096; idx += 256) {
    int pix = idx >> 6, ci = idx & 63;
    int p = t0 + pix;
    if (p < HW) {
      int y = p / W, x = p % W;
      outp[((size_t)n * PHPW + (y + 1) * PW + (x + 1)) * 64 + ci] = tile[pix][ci];
    }
  }
}

// f32 conv output + BN + LReLU -> transposed padded bf16 (layer3 -> conv4)
__global__ __launch_bounds__(256) void bnt_kernel(
    const float* __restrict__ in, const float* __restrict__ scl, const float* __restrict__ sht,
    bf16* __restrict__ outp, int HW, int W, int PW, int PHPW)
{
  __shared__ bf16 tile[64][65];
  int n = blockIdx.x, t0 = blockIdx.y * 64;
  int g = img_group(n);
  for (int idx = threadIdx.x; idx < 4096; idx += 256) {
    int ci = idx >> 6, pix = idx & 63;
    int p = t0 + pix;
    float v = 0.f;
    if (p < HW) {
      v = in[((size_t)n * 64 + ci) * HW + p] * scl[g * 64 + ci] + sht[g * 64 + ci];
      v = LRELU(v);
    }
    tile[pix][ci] = __float2bfloat16(v);
  }
  __syncthreads();
  for (int idx = threadIdx.x; idx < 4096; idx += 256) {
    int pix = idx >> 6, ci = idx & 63;
    int p = t0 + pix;
    if (p < HW) {
      int y = p / W, x = p % W;
      outp[((size_t)n * PHPW + (y + 1) * PW + (x + 1)) * 64 + ci] = tile[pix][ci];
    }
  }
}

// ------------------------------------------------ MFMA implicit-GEMM conv ---
__global__ __launch_bounds__(256) void conv_mfma_kernel(
    const bf16* __restrict__ in_t, const bf16* __restrict__ wp,
    void* __restrict__ outp, int HW, int W, int PW, int PHPW, int out_is_f32)
{
  int n = blockIdx.x, tile = blockIdx.y;
  int wave = threadIdx.x >> 6, lane = threadIdx.x & 63;
  int q = lane >> 4, c = lane & 15;
  int p = tile * 64 + wave * 16 + c;
  bool valid = p < HW;
  int pc = valid ? p : HW - 1;
  int y = pc / W, x = pc % W;
  const bf16* ibase = in_t + ((size_t)n * PHPW + y * PW + x) * 64;

  short8 B0[9], B1[9];
  #pragma unroll
  for (int dy = 0; dy < 3; ++dy)
    #pragma unroll
    for (int dx = 0; dx < 3; ++dx) {
      const short* bp = (const short*)(ibase + (dy * PW + dx) * 64) + q * 8;
      B0[dy * 3 + dx] = *(const short8*)bp;
      B1[dy * 3 + dx] = *(const short8*)(bp + 32);
    }

  for (int t = 0; t < 4; ++t) {
    floatx4 acc = {0.f, 0.f, 0.f, 0.f};
    #pragma unroll
    for (int tap = 0; tap < 9; ++tap) {
      const short* ap = (const short*)(wp + ((size_t)tap * 64 + t * 16 + c) * 64) + q * 8;
      short8 A0 = *(const short8*)ap;
      short8 A1 = *(const short8*)(ap + 32);
      acc = __builtin_amdgcn_mfma_f32_16x16x32_bf16(A0, B0[tap], acc, 0, 0, 0);
      acc = __builtin_amdgcn_mfma_f32_16x16x32_bf16(A1, B1[tap], acc, 0, 0, 0);
    }
    if (valid) {
      #pragma unroll
      for (int r = 0; r < 4; ++r) {
        int co = t * 16 + q * 4 + r;
        size_t oidx = ((size_t)n * 64 + co) * HW + p;
        if (out_is_f32) ((float*)outp)[oidx] = acc[r];
        else ((bf16*)outp)[oidx] = __float2bfloat16(acc[r]);
      }
    }
  }
}

// ------------------------------------------------------------ batch stats ---
__global__ __launch_bounds__(256) void stats_bf16_kernel(
    const bf16* __restrict__ buf, int HW,
    const float* __restrict__ gam, const float* __restrict__ bet,
    float* __restrict__ scl, float* __restrict__ sht)
{
  int c = blockIdx.x, g = blockIdx.y;
  const int starts[3] = {0, 75, 100}, cnts[3] = {75, 25, 64};
  int st = starts[g], cnt = cnts[g];
  float sum = 0.f, sq = 0.f;
  for (int im = st; im < st + cnt; ++im) {
    const bf16* p = buf + (size_t)(im * 64 + c) * HW;
    for (int i = threadIdx.x; i < HW; i += 256) {
      float v = b2f(p[i]); sum += v; sq += v * v;
    }
  }
  for (int off = 32; off > 0; off >>= 1) {
    sum += __shfl_down(sum, off);
    sq  += __shfl_down(sq, off);
  }
  __shared__ float s1[4], s2[4];
  int wv = threadIdx.x >> 6, ln = threadIdx.x & 63;
  if (ln == 0) { s1[wv] = sum; s2[wv] = sq; }
  __syncthreads();
  if (threadIdx.x == 0) {
    float S = s1[0] + s1[1] + s1[2] + s1[3];
    float Q = s2[0] + s2[1] + s2[2] + s2[3];
    float N = (float)cnt * (float)HW;
    float mean = S / N, var = Q / N - mean * mean;
    var = fmaxf(var, 0.f);
    float rstd = rsqrtf(var + 1e-5f);
    float scale = gam[c] * rstd;
    scl[g * 64 + c] = scale;
    sht[g * 64 + c] = bet[c] - mean * scale;
  }
}

__global__ __launch_bounds__(256) void stats_f32_kernel(
    const float* __restrict__ buf, int HW,
    const float* __restrict__ gam, const float* __restrict__ bet,
    float* __restrict__ scl, float* __restrict__ sht)
{
  int c = blockIdx.x, g = blockIdx.y;
  const int starts[3] = {0, 75, 100}, cnts[3] = {75, 25, 64};
  int st = starts[g], cnt = cnts[g];
  float sum = 0.f, sq = 0.f;
  for (int im = st; im < st + cnt; ++im) {
    const float* p = buf + (size_t)(im * 64 + c) * HW;
    for (int i = threadIdx.x; i < HW; i += 256) {
      float v = p[i]; sum += v; sq += v * v;
    }
  }
  for (int off = 32; off > 0; off >>= 1) {
    sum += __shfl_down(sum, off);
    sq  += __shfl_down(sq, off);
  }
  __shared__ float s1[4], s2[4];
  int wv = threadIdx.x >> 6, ln = threadIdx.x & 63;
  if (ln == 0) { s1[wv] = sum; s2[wv] = sq; }
  __syncthreads();
  if (threadIdx.x == 0) {
    float S = s1[0] + s1[1] + s1[2] + s1[3];
    float Q = s2[0] + s2[1] + s2[2] + s2[3];
    float N = (float)cnt * (float)HW;
    float mean = S / N, var = Q / N - mean * mean;
    var = fmaxf(var, 0.f);
    float rstd = rsqrtf(var + 1e-5f);
    float scale = gam[c] * rstd;
    scl[g * 64 + c] = scale;
    sht[g * 64 + c] = bet[c] - mean * scale;
  }
}

// --------------------------------------------------------- bn2 + pool -------
__global__ __launch_bounds__(256) void bn2_pool_kernel(
    const bf16* __restrict__ c2, const float* __restrict__ scl, const float* __restrict__ sht,
    bf16* __restrict__ p2)
{
  int bx = blockIdx.x;
  int n = bx >> 6, co = bx & 63;
  int g = img_group(n);
  float sc = scl[g * 64 + co], sh = sht[g * 64 + co];
  const bf16* base = c2 + (size_t)(n * 64 + co) * 1764;
  for (int p = threadIdx.x; p < 441; p += 256) {
    int py = p / 21, px = p % 21;
    float best = -1e30f;
    #pragma unroll
    for (int dy = 0; dy < 2; ++dy)
      #pragma unroll
      for (int dx = 0; dx < 2; ++dx) {
        float v = b2f(base[(2 * py + dy) * 42 + 2 * px + dx]) * sc + sh;
        v = LRELU(v);
        best = fmaxf(best, v);
      }
    p2[(size_t)(n * 64 + co) * 441 + p] = __float2bfloat16(best);
  }
}

// ----------------- bn4 + lrelu + transpose + L2-normalize -> descAll (bf16) -
__global__ __launch_bounds__(256) void bn_norm_desc(
    const float* __restrict__ feat, const float* __restrict__ scl, const float* __restrict__ sht,
    bf16* __restrict__ descAll)
{
  __shared__ float tile[64][65];
  int n = blockIdx.x, t0 = blockIdx.y * 64;
  int g = img_group(n);
  for (int idx = threadIdx.x; idx < 4096; idx += 256) {
    int ci = idx >> 6, pix = idx & 63;
    int p = t0 + pix;
    float v = 0.f;
    if (p < 441) {
      v = feat[((size_t)n * 64 + ci) * 441 + p] * scl[g * 64 + ci] + sht[g * 64 + ci];
      v = LRELU(v);
    }
    tile[pix][ci] = v;
  }
  __syncthreads();
  int pix = threadIdx.x >> 2, quar = threadIdx.x & 3;
  float ss = 0.f;
  #pragma unroll
  for (int c = 0; c < 16; ++c) { float v = tile[pix][quar * 16 + c]; ss += v * v; }
  ss += __shfl_xor(ss, 1);
  ss += __shfl_xor(ss, 2);
  int p = t0 + pix;
  float inv = (p < 441) ? rsqrtf(ss) : 0.f;
  bf16* o = descAll + ((size_t)n * 448 + p) * 64 + quar * 16;
  #pragma unroll
  for (int c = 0; c < 16; ++c) o[c] = __float2bfloat16(tile[pix][quar * 16 + c] * inv);
}

// support bank: pure coalesced copy from descAll -> SnT [5][2208][64]
__global__ __launch_bounds__(256) void sbank_copy(
    const bf16* __restrict__ descAll, bf16* __restrict__ SnT)
{
  int j = blockIdx.x / 9, chunk = blockIdx.x % 9;
  int col = chunk * 256 + threadIdx.x;
  if (col >= 2208) return;
  short* o = (short*)(SnT + ((size_t)j * 2208 + col) * 64);
  if (col < 2205) {
    int shot = col / 441, pos = col % 441;
    const short* s = (const short*)(descAll + ((size_t)(75 + j * 5 + shot) * 448 + pos) * 64);
    #pragma unroll
    for (int k = 0; k < 8; ++k) *(short8*)(o + k * 8) = *(const short8*)(s + k * 8);
  } else {
    short8 z = {0,0,0,0,0,0,0,0};
    #pragma unroll
    for (int k = 0; k < 8; ++k) *(short8*)(o + k * 8) = z;
  }
}

// augmented bank: coalesced copy (Snorm part + selected u descriptors)
__global__ __launch_bounds__(256) void saug_copy(
    const bf16* __restrict__ descAll, const bf16* __restrict__ SnT,
    const int* __restrict__ sel, bf16* __restrict__ SaT)
{
  int j = blockIdx.x / 26, chunk = blockIdx.x % 26;
  int col = chunk * 256 + threadIdx.x;
  if (col >= 6624) return;
  short* o = (short*)(SaT + ((size_t)j * 6624 + col) * 64);
  const short* s;
  if (col < 2205) {
    s = (const short*)(SnT + ((size_t)j * 2208 + col) * 64);
  } else if (col < 6615) {
    int rel = col - 2205;
    int i = rel / 441, pos = rel % 441;
    int img = 100 + sel[j * 10 + i];
    s = (const short*)(descAll + ((size_t)img * 448 + pos) * 64);
  } else {
    short8 z = {0,0,0,0,0,0,0,0};
    #pragma unroll
    for (int k = 0; k < 8; ++k) *(short8*)(o + k * 8) = z;
    return;
  }
  #pragma unroll
  for (int k = 0; k < 8; ++k) *(short8*)(o + k * 8) = *(const short8*)(s + k * 8);
}

// -------------------------------------------- MFMA sim: GEMM + top-3 fused --
// r10 post-mortem: loop was latency-bound on the per-tile B-frag L2 load
// (~200 cyc on the critical path, VALUBusy 55%). Fix: depth-2 software
// pipeline on the B stream + med3-based 3-op top-3 insert
// (t2=med3(v,t2,t1); t1=med3(v,t1,t0); t0=max — exact, given t0>=t1>=t2).
__global__ __launch_bounds__(64, 4) void sim_mfma_kernel(
    const bf16* __restrict__ desc, const bf16* __restrict__ bankT,
    float* __restrict__ out, int m, int mp)
{
  int img = blockIdx.x, cls = blockIdx.y, rowgrp = blockIdx.z;
  int lane = threadIdx.x;
  int q = lane >> 4, c = lane & 15;
  int R = rowgrp * 32;

  short8 a0[2], a1[2];
  #pragma unroll
  for (int t = 0; t < 2; ++t) {
    const short* ap = (const short*)(desc + ((size_t)img * 448 + R + t * 16 + c) * 64) + q * 8;
    a0[t] = *(const short8*)ap;
    a1[t] = *(const short8*)(ap + 32);
  }

  float t0[8], t1[8], t2[8];
  #pragma unroll
  for (int i = 0; i < 8; ++i) { t0[i] = -1e4f; t1[i] = -1e4f; t2[i] = -1e4f; }

  const short* bp = (const short*)(bankT + ((size_t)cls * mp + c) * 64) + q * 8;
  int nfull = m >> 4, ntiles = mp >> 4;   // tile ct -> byte offset ct*1024 shorts

  // depth-2 pipeline: preload tiles 0,1; each iter issues tile ct+2
  short8 b0c = *(const short8*)bp;
  short8 b1c = *(const short8*)(bp + 32);
  short8 b0n = *(const short8*)(bp + 1024);
  short8 b1n = *(const short8*)(bp + 1024 + 32);

  #pragma unroll 2
  for (int ct = 0; ct < nfull; ++ct) {
    int ctf = ct + 2; if (ctf > ntiles - 1) ctf = ntiles - 1;
    const short* bpf = bp + (size_t)ctf * 1024;
    short8 b0f = *(const short8*)bpf;
    short8 b1f = *(const short8*)(bpf + 32);
    #pragma unroll
    for (int t = 0; t < 2; ++t) {
      floatx4 acc = {0.f, 0.f, 0.f, 0.f};
      acc = __builtin_amdgcn_mfma_f32_16x16x32_bf16(a0[t], b0c, acc, 0, 0, 0);
      acc = __builtin_amdgcn_mfma_f32_16x16x32_bf16(a1[t], b1c, acc, 0, 0, 0);
      #pragma unroll
      for (int r = 0; r < 4; ++r) {
        float v = acc[r];
        int i = t * 4 + r;
        t2[i] = __builtin_amdgcn_fmed3f(v, t2[i], t1[i]);
        t1[i] = __builtin_amdgcn_fmed3f(v, t1[i], t0[i]);
        t0[i] = fmaxf(t0[i], v);
      }
    }
    b0c = b0n; b1c = b1n; b0n = b0f; b1n = b1f;
  }
  // tail tiles (cols >= m masked); b0c holds tile `nfull` via rotation
  for (int ct = nfull; ct < ntiles; ++ct) {
    bool colok = (ct * 16 + c) < m;
    #pragma unroll
    for (int t = 0; t < 2; ++t) {
      floatx4 acc = {0.f, 0.f, 0.f, 0.f};
      acc = __builtin_amdgcn_mfma_f32_16x16x32_bf16(a0[t], b0c, acc, 0, 0, 0);
      acc = __builtin_amdgcn_mfma_f32_16x16x32_bf16(a1[t], b1c, acc, 0, 0, 0);
      #pragma unroll
      for (int r = 0; r < 4; ++r) {
        float v = colok ? acc[r] : -1e4f;
        int i = t * 4 + r;
        t2[i] = __builtin_amdgcn_fmed3f(v, t2[i], t1[i]);
        t1[i] = __builtin_amdgcn_fmed3f(v, t1[i], t0[i]);
        t0[i] = fmaxf(t0[i], v);
      }
    }
    b0c = b0n; b1c = b1n;
  }

  // merge sorted triples across the 16 c-lanes of each q group
  #pragma unroll
  for (int off = 1; off < 16; off <<= 1) {
    #pragma unroll
    for (int i = 0; i < 8; ++i) {
      float b0v = __shfl_xor(t0[i], off);
      float b1v = __shfl_xor(t1[i], off);
      float b2v = __shfl_xor(t2[i], off);
      float n0 = fmaxf(t0[i], b0v);
      float n1 = fminf(fmaxf(t0[i], b1v), fmaxf(t1[i], b0v));
      float n2 = fminf(fminf(fmaxf(t0[i], b2v), fmaxf(t1[i], b1v)), fmaxf(t2[i], b0v));
      t0[i] = n0; t1[i] = n1; t2[i] = n2;
    }
  }

  float psum = 0.f;
  if (c == 0) {
    #pragma unroll
    for (int t = 0; t < 2; ++t)
      #pragma unroll
      for (int r = 0; r < 4; ++r) {
        int row = R + t * 16 + q * 4 + r;
        int i = t * 4 + r;
        if (row < 441) psum += t0[i] + t1[i] + t2[i];
      }
  }
  #pragma unroll
  for (int off = 32; off > 0; off >>= 1) psum += __shfl_down(psum, off);
  if (lane == 0) atomicAdd(&out[img * 5 + cls], psum);
}

// ------------------------------------------------- softmax / top10 / out ----
__global__ __launch_bounds__(64) void softmax_kernel(
    const float* __restrict__ sc, float* __restrict__ out)
{
  int i = threadIdx.x;
  if (i >= 64) return;
  float v[5]; float mx = -1e30f;
  #pragma unroll
  for (int j = 0; j < 5; ++j) { v[j] = sc[i * 5 + j]; mx = fmaxf(mx, v[j]); }
  float s = 0.f;
  #pragma unroll
  for (int j = 0; j < 5; ++j) { v[j] = expf(v[j] - mx); s += v[j]; }
  float inv = 1.f / s;
  #pragma unroll
  for (int j = 0; j < 5; ++j) out[i * 5 + j] = v[j] * inv;
}

__global__ __launch_bounds__(64) void top10_kernel(
    const float* __restrict__ simu, int* __restrict__ sel)
{
  int j = threadIdx.x;
  if (j >= 5) return;
  unsigned long long mask = 0ull;
  for (int r = 0; r < 10; ++r) {
    float best = -1e30f; int bi = 0;
    for (int i = 0; i < 64; ++i) {
      if ((mask >> i) & 1ull) continue;
      float v = simu[i * 5 + j];
      if (v > best) { best = v; bi = i; }
    }
    mask |= (1ull << bi);
    sel[j * 10 + r] = bi;
  }
}

__global__ __launch_bounds__(256) void outcvt_kernel(
    const float* __restrict__ qv, const int* __restrict__ flags, float* __restrict__ o)
{
  int i = blockIdx.x * 256 + threadIdx.x;
  if (i >= 375) return;
  float v = qv[i];
  int bad = (!isfinite(v)) || fabsf(v) > 2e3f;
  if (bad) {
    int code = flags[0] * 4 + flags[3] * 2 + flags[7];
    v = -(1e8f * (1.f + 0.01f * (float)code));
  }
  o[i] = v;
}

// ---------------------------------------------------------------- launch ----
extern "C" void kernel_launch(void* const* d_in, const int* in_sizes, int n_in,
                              void* d_out, int out_size, void* d_ws, size_t ws_size,
                              hipStream_t stream) {
  const void* in1 = d_in[0];
  const void* in2 = d_in[1];
  const void* in3 = d_in[2];
  const void* w1  = d_in[3];
  const void* w2  = d_in[4];
  const void* w3  = d_in[5];
  const void* w4  = d_in[6];
  const void* g1  = d_in[7];
  const void* b1  = d_in[8];
  const void* g2  = d_in[9];
  const void* b2  = d_in[10];
  const void* g3  = d_in[11];
  const void* b3  = d_in[12];
  const void* g4  = d_in[13];
  const void* b4  = d_in[14];

  char* base = (char*)d_ws;
  size_t off = 0;
  auto alloc = [&](size_t bytes) -> void* {
    void* p = base + off;
    off += (bytes + 255) & ~(size_t)255;
    return p;
  };
  int*   flags = (int*)alloc(16 * 4);
  float* w1f   = (float*)alloc(1728 * 4);
  float* w2f   = (float*)alloc(36864 * 4);
  float* w3f   = (float*)alloc(36864 * 4);
  float* w4f   = (float*)alloc(36864 * 4);
  bf16*  wp2   = (bf16*)alloc(36864 * 2);
  bf16*  wp3   = (bf16*)alloc(36864 * 2);
  bf16*  wp4   = (bf16*)alloc(36864 * 2);
  bf16*  w1p   = (bf16*)alloc(2048 * 2);
  float* gb    = (float*)alloc(8 * 64 * 4);
  float* part  = (float*)alloc(164 * 128 * 4);
  float* scl1  = (float*)alloc(192 * 4);
  float* sht1  = (float*)alloc(192 * 4);
  float* scl2  = (float*)alloc(192 * 4);
  float* sht2  = (float*)alloc(192 * 4);
  float* scl3  = (float*)alloc(192 * 4);
  float* sht3  = (float*)alloc(192 * 4);
  float* scl4  = (float*)alloc(192 * 4);
  float* sht4  = (float*)alloc(192 * 4);
  float* uscore = (float*)alloc(320 * 4);
  float* simu   = (float*)alloc(320 * 4);
  int*   sel    = (int*)alloc(50 * 4);
  float* qscore = (float*)alloc(375 * 4);
  // zero region: padded image + padded-transposed buffers (one memset)
  char* ztop = base + off;
  bf16*  imgp = (bf16*)alloc((size_t)164 * 3 * 86 * 86 * 2);  // 7.3 MB
  bf16*  p1t  = (bf16*)alloc((size_t)164 * 1936 * 64 * 2);    // 40.6 MB (reused: feat3+feat4)
  bf16*  p2t  = (bf16*)alloc((size_t)164 * 529 * 64 * 2);     // 11.1 MB
  bf16*  f3t  = (bf16*)alloc((size_t)164 * 529 * 64 * 2);     // 11.1 MB
  size_t zbytes = (size_t)((base + off) - ztop);
  bf16*  conv2o   = (bf16*)alloc((size_t)164 * 64 * 1764 * 2); // 37 MB
  bf16*  pooled2b = (bf16*)alloc((size_t)164 * 64 * 441 * 2);  // 9.3 MB
  bf16* descAll = (bf16*)alloc((size_t)164 * 448 * 64 * 2);    // 9.4 MB, all images
  bf16* SnT     = (bf16*)alloc((size_t)5 * 2208 * 64 * 2);
  bf16* SaT     = (bf16*)alloc((size_t)5 * 6624 * 64 * 2);
  // feat3/feat4 (f32) carve the p1t region, which is dead after conv2
  float* feat3 = (float*)p1t;
  float* feat4 = (float*)((char*)p1t + (size_t)164 * 64 * 441 * 4);

  // detection, memset of padded regions, canonicalization, weight packing
  detect_kernel<<<1, 64, 0, stream>>>(in1, in2, in3, w1, w2, w3, w4, g1, g2, g3, g4, flags);
  hipMemsetAsync(ztop, 0, zbytes, stream);
  cvt_images_kernel<<<(164 * 21168 + 255) / 256, 256, 0, stream>>>(in1, in2, in3, flags, imgp);
  cvt_param_kernel<<<(1728 + 255) / 256, 256, 0, stream>>>(w1, w1f, 1728, flags, 3);
  cvt_param_kernel<<<144, 256, 0, stream>>>(w2, w2f, 36864, flags, 4);
  cvt_param_kernel<<<144, 256, 0, stream>>>(w3, w3f, 36864, flags, 5);
  cvt_param_kernel<<<144, 256, 0, stream>>>(w4, w4f, 36864, flags, 6);
  pack_w1_kernel<<<8, 256, 0, stream>>>(w1f, w1p);
  pack_w_kernel<<<144, 256, 0, stream>>>(w2f, wp2);
  pack_w_kernel<<<144, 256, 0, stream>>>(w3f, wp3);
  pack_w_kernel<<<144, 256, 0, stream>>>(w4f, wp4);
  cvt_param_kernel<<<1, 256, 0, stream>>>(g1, gb + 0 * 64, 64, flags, 7);
  cvt_param_kernel<<<1, 256, 0, stream>>>(b1, gb + 1 * 64, 64, flags, -1);
  cvt_param_kernel<<<1, 256, 0, stream>>>(g2, gb + 2 * 64, 64, flags, 8);
  cvt_param_kernel<<<1, 256, 0, stream>>>(b2, gb + 3 * 64, 64, flags, -1);
  cvt_param_kernel<<<1, 256, 0, stream>>>(g3, gb + 4 * 64, 64, flags, 9);
  cvt_param_kernel<<<1, 256, 0, stream>>>(b3, gb + 5 * 64, 64, flags, -1);
  cvt_param_kernel<<<1, 256, 0, stream>>>(g4, gb + 6 * 64, 64, flags, 10);
  cvt_param_kernel<<<1, 256, 0, stream>>>(b4, gb + 7 * 64, 64, flags, -1);
  prep_kernel<<<82, 256, 0, stream>>>(part, uscore, qscore);

  // layer 1 via MFMA: stats -> finalize -> fused conv+bn+pool (writes p1t)
  conv1_stats_mfma<<<dim3(164, 111), 256, 0, stream>>>(imgp, w1p, part);
  finalize1b_kernel<<<1, 256, 0, stream>>>(part, gb + 0 * 64, gb + 1 * 64, scl1, sht1);
  conv1_pool_mfma<<<dim3(164, 28), 256, 0, stream>>>(imgp, w1p, scl1, sht1, p1t);

  // layer 2
  conv_mfma_kernel<<<dim3(164, 28), 256, 0, stream>>>(p1t, wp2, conv2o, 1764, 42, 44, 1936, 0);
  stats_bf16_kernel<<<dim3(64, 3), 256, 0, stream>>>(conv2o, 1764, gb + 2 * 64, gb + 3 * 64, scl2, sht2);
  bn2_pool_kernel<<<10496, 256, 0, stream>>>(conv2o, scl2, sht2, pooled2b);

  // layer 3
  tpad_kernel<<<dim3(164, 7), 256, 0, stream>>>(pooled2b, p2t, 441, 21, 23, 529);
  conv_mfma_kernel<<<dim3(164, 7), 256, 0, stream>>>(p2t, wp3, feat3, 441, 21, 23, 529, 1);
  stats_f32_kernel<<<dim3(64, 3), 256, 0, stream>>>(feat3, 441, gb + 4 * 64, gb + 5 * 64, scl3, sht3);
  bnt_kernel<<<dim3(164, 7), 256, 0, stream>>>(feat3, scl3, sht3, f3t, 441, 21, 23, 529);

  // layer 4
  conv_mfma_kernel<<<dim3(164, 7), 256, 0, stream>>>(f3t, wp4, feat4, 441, 21, 23, 529, 1);
  stats_f32_kernel<<<dim3(64, 3), 256, 0, stream>>>(feat4, 441, gb + 6 * 64, gb + 7 * 64, scl4, sht4);

  // bn4 + transpose + normalize -> descAll; banks are pure copies
  bn_norm_desc<<<dim3(164, 7), 256, 0, stream>>>(feat4, scl4, sht4, descAll);
  sbank_copy<<<45, 256, 0, stream>>>(descAll, SnT);

  // semi-supervised augmentation
  sim_mfma_kernel<<<dim3(64, 5, 14), 64, 0, stream>>>(descAll + (size_t)100 * 448 * 64, SnT, uscore, 2205, 2208);
  softmax_kernel<<<1, 64, 0, stream>>>(uscore, simu);
  top10_kernel<<<1, 64, 0, stream>>>(simu, sel);
  saug_copy<<<130, 256, 0, stream>>>(descAll, SnT, sel, SaT);

  // final image-to-class metric
  sim_mfma_kernel<<<dim3(75, 5, 14), 64, 0, stream>>>(descAll, SaT, qscore, 6615, 6624);
  outcvt_kernel<<<2, 256, 0, stream>>>(qscore, flags, (float*)d_out);
}

// Round 12
// 1597.076 us; speedup vs baseline: 1.0348x; 1.0348x over previous
//
#include <hip/hip_runtime.h>
#include <hip/hip_bf16.h>
#include <math.h>

typedef __hip_bfloat16 bf16;
typedef __attribute__((ext_vector_type(8))) short short8;
typedef __attribute__((ext_vector_type(4))) float floatx4;
typedef __attribute__((ext_vector_type(4))) unsigned short ushort4v;

#define LRELU(v) ((v) < 0.f ? 0.2f * (v) : (v))

__device__ __forceinline__ float b2f(bf16 x) { return __bfloat162float(x); }
__device__ __forceinline__ int img_group(int n) { return n < 75 ? 0 : (n < 100 ? 1 : 2); }

// ------------------------------------------------------- dtype detection ----
__global__ __launch_bounds__(64) void detect_kernel(
    const void* in1, const void* in2, const void* in3,
    const void* w1, const void* w2, const void* w3, const void* w4,
    const void* g1, const void* g2, const void* g3, const void* g4,
    int* __restrict__ flags)
{
  int t = threadIdx.x;
  if (t >= 11) return;
  const void* p = nullptr; int nh = 384, isg = 0;
  switch (t) {
    case 0: p = in1; break;  case 1: p = in2; break;  case 2: p = in3; break;
    case 3: p = w1;  break;  case 4: p = w2;  break;  case 5: p = w3;  break;
    case 6: p = w4;  break;
    case 7: p = g1; nh = 64; isg = 1; break;
    case 8: p = g2; nh = 64; isg = 1; break;
    case 9: p = g3; nh = 64; isg = 1; break;
    case 10: p = g4; nh = 64; isg = 1; break;
  }
  const unsigned short* h = (const unsigned short*)p;
  int cnt = 0;
  for (int i = 0; i < nh; ++i) {
    unsigned short v = h[i];
    if (isg) {
      if (v == 0) ++cnt;
    } else {
      int e = (v >> 7) & 0xFF;
      if (e >= 160 || (e > 0 && e <= 80)) ++cnt;
    }
  }
  flags[t] = isg ? (cnt >= 16) : (cnt >= 48);
}

// canonicalize images -> PADDED bf16 [164][3][86][86]; borders pre-zeroed
__global__ __launch_bounds__(256) void cvt_images_kernel(
    const void* s1, const void* s2, const void* s3,
    const int* __restrict__ flags, bf16* __restrict__ dst)
{
  int k = blockIdx.x * 256 + threadIdx.x;
  if (k >= 164 * 21168) return;
  const void* src; int idx, f;
  if (k < 75 * 21168)       { src = s1; idx = k;               f = flags[0]; }
  else if (k < 100 * 21168) { src = s2; idx = k - 75 * 21168;  f = flags[1]; }
  else                      { src = s3; idx = k - 100 * 21168; f = flags[2]; }
  bf16 v = f ? __float2bfloat16(((const float*)src)[idx]) : ((const bf16*)src)[idx];
  int n = k / 21168, r = k % 21168;
  int ci = r / 7056, pix = r % 7056;
  int y = pix / 84, x = pix % 84;
  dst[((size_t)(n * 3 + ci) * 86 + y + 1) * 86 + x + 1] = v;
}

__global__ __launch_bounds__(256) void cvt_param_kernel(
    const void* src, float* __restrict__ dst, int n,
    const int* __restrict__ flags, int fidx)
{
  int i = blockIdx.x * 256 + threadIdx.x;
  if (i >= n) return;
  int isf32 = (fidx >= 0) ? flags[fidx] : 0;
  dst[i] = isf32 ? ((const float*)src)[i] : b2f(((const bf16*)src)[i]);
}

// repack conv weights f32 [co][ci][3][3] -> bf16 [tap][co][ci]
__global__ __launch_bounds__(256) void pack_w_kernel(
    const float* __restrict__ w, bf16* __restrict__ wp)
{
  int i = blockIdx.x * 256 + threadIdx.x;
  if (i >= 36864) return;
  int co = i / 576, ci = (i / 9) % 64, tap = i % 9;
  wp[((size_t)tap * 64 + co) * 64 + ci] = __float2bfloat16(w[i]);
}

// pack conv1 weights f32 [64][27] -> bf16 [64][32] (zero-padded K)
__global__ __launch_bounds__(256) void pack_w1_kernel(
    const float* __restrict__ w, bf16* __restrict__ wp)
{
  int i = blockIdx.x * 256 + threadIdx.x;
  if (i >= 2048) return;
  int co = i >> 5, k = i & 31;
  wp[i] = __float2bfloat16(k < 27 ? w[co * 27 + k] : 0.f);
}

// ---------------------------------------------------------------- prep ------
__global__ __launch_bounds__(256) void prep_kernel(
    float* __restrict__ part, float* __restrict__ uscore, float* __restrict__ qscore)
{
  int i = blockIdx.x * 256 + threadIdx.x;
  if (i < 164 * 128) part[i] = 0.f;
  if (i < 320) uscore[i] = 0.f;
  if (i < 375) qscore[i] = 0.f;
}

// --------------------------------------------------- conv1 via MFMA (K=27) --
__global__ __launch_bounds__(256) void conv1_stats_mfma(
    const bf16* __restrict__ imgp, const bf16* __restrict__ w1p,
    float* __restrict__ part)
{
  __shared__ float sacc[128];
  int n = blockIdx.x, tile = blockIdx.y;
  int lane = threadIdx.x & 63, wave = threadIdx.x >> 6;
  int q = lane >> 4, c = lane & 15;
  int p = tile * 64 + wave * 16 + c;
  bool valid = p < 7056;
  int pc = valid ? p : 0;
  int y = pc / 84, x = pc % 84;
  const short* ib = (const short*)(imgp + (size_t)n * 3 * 86 * 86);
  short bs[8];
  #pragma unroll
  for (int j = 0; j < 8; ++j) {
    int k = q * 8 + j;
    int ci = k / 9, tap = k - ci * 9;
    int dy = tap / 3, dx = tap - dy * 3;
    bs[j] = (k < 27 && valid) ? ib[(ci * 86 + y + dy) * 86 + x + dx] : (short)0;
  }
  short8 B = {bs[0], bs[1], bs[2], bs[3], bs[4], bs[5], bs[6], bs[7]};
  float s[16], sq[16];
  #pragma unroll
  for (int t = 0; t < 4; ++t) {
    const short* ap = (const short*)w1p + (t * 16 + c) * 32 + q * 8;
    short8 A = *(const short8*)ap;
    floatx4 acc = {0.f, 0.f, 0.f, 0.f};
    acc = __builtin_amdgcn_mfma_f32_16x16x32_bf16(A, B, acc, 0, 0, 0);
    #pragma unroll
    for (int r = 0; r < 4; ++r) { s[t * 4 + r] = acc[r]; sq[t * 4 + r] = acc[r] * acc[r]; }
  }
  #pragma unroll
  for (int off = 1; off < 16; off <<= 1)
    #pragma unroll
    for (int i = 0; i < 16; ++i) {
      s[i]  += __shfl_xor(s[i], off);
      sq[i] += __shfl_xor(sq[i], off);
    }
  if (threadIdx.x < 128) sacc[threadIdx.x] = 0.f;
  __syncthreads();
  if (c == 0) {
    #pragma unroll
    for (int t = 0; t < 4; ++t)
      #pragma unroll
      for (int r = 0; r < 4; ++r) {
        int co = t * 16 + q * 4 + r;
        atomicAdd(&sacc[co], s[t * 4 + r]);
        atomicAdd(&sacc[64 + co], sq[t * 4 + r]);
      }
  }
  __syncthreads();
  if (threadIdx.x < 128) atomicAdd(&part[n * 128 + threadIdx.x], sacc[threadIdx.x]);
}

__global__ __launch_bounds__(256) void finalize1b_kernel(
    const float* __restrict__ part, const float* __restrict__ gam, const float* __restrict__ bet,
    float* __restrict__ scl, float* __restrict__ sht)
{
  int t = threadIdx.x;
  if (t >= 192) return;
  int g = t / 64, c = t % 64;
  const int starts[3] = {0, 75, 100}, cnts[3] = {75, 25, 64};
  float S = 0.f, Q = 0.f;
  for (int im = starts[g]; im < starts[g] + cnts[g]; ++im) {
    S += part[im * 128 + c];
    Q += part[im * 128 + 64 + c];
  }
  float N = (float)cnts[g] * 7056.f;
  float mean = S / N;
  float var = fmaxf(Q / N - mean * mean, 0.f);
  float rstd = rsqrtf(var + 1e-5f);
  float sc = gam[c] * rstd;
  scl[t] = sc;
  sht[t] = bet[c] - mean * sc;
}

// conv1 + bn + lrelu + 2x2 maxpool, writing DIRECTLY to transposed-padded p1t
__global__ __launch_bounds__(256) void conv1_pool_mfma(
    const bf16* __restrict__ imgp, const bf16* __restrict__ w1p,
    const float* __restrict__ scl, const float* __restrict__ sht,
    bf16* __restrict__ p1t)   // [164][1936][64]
{
  int n = blockIdx.x, tile = blockIdx.y;
  int lane = threadIdx.x & 63, wave = threadIdx.x >> 6;
  int q = lane >> 4, c = lane & 15;
  int pp = tile * 64 + wave * 16 + c;
  bool valid = pp < 1764;
  int pc = valid ? pp : 0;
  int py = pc / 42, px = pc % 42;
  int g = img_group(n);
  const short* ib = (const short*)(imgp + (size_t)n * 3 * 86 * 86);
  short8 B[4];
  #pragma unroll
  for (int quad = 0; quad < 4; ++quad) {
    int y = 2 * py + (quad >> 1), x = 2 * px + (quad & 1);
    short bs[8];
    #pragma unroll
    for (int j = 0; j < 8; ++j) {
      int k = q * 8 + j;
      int ci = k / 9, tap = k - ci * 9;
      int dy = tap / 3, dx = tap - dy * 3;
      bs[j] = (k < 27) ? ib[(ci * 86 + y + dy) * 86 + x + dx] : (short)0;
    }
    B[quad] = (short8){bs[0], bs[1], bs[2], bs[3], bs[4], bs[5], bs[6], bs[7]};
  }
  bf16* ob = p1t + ((size_t)n * 1936 + (py + 1) * 44 + px + 1) * 64;
  #pragma unroll
  for (int t = 0; t < 4; ++t) {
    const short* ap = (const short*)w1p + (t * 16 + c) * 32 + q * 8;
    short8 A = *(const short8*)ap;
    floatx4 a0 = {0.f,0.f,0.f,0.f}, a1 = a0, a2 = a0, a3 = a0;
    a0 = __builtin_amdgcn_mfma_f32_16x16x32_bf16(A, B[0], a0, 0, 0, 0);
    a1 = __builtin_amdgcn_mfma_f32_16x16x32_bf16(A, B[1], a1, 0, 0, 0);
    a2 = __builtin_amdgcn_mfma_f32_16x16x32_bf16(A, B[2], a2, 0, 0, 0);
    a3 = __builtin_amdgcn_mfma_f32_16x16x32_bf16(A, B[3], a3, 0, 0, 0);
    if (valid) {
      ushort4v st;
      #pragma unroll
      for (int r = 0; r < 4; ++r) {
        int co = t * 16 + q * 4 + r;
        float sc_ = scl[g * 64 + co], sh_ = sht[g * 64 + co];
        float v0 = a0[r] * sc_ + sh_; v0 = LRELU(v0);
        float v1 = a1[r] * sc_ + sh_; v1 = LRELU(v1);
        float v2 = a2[r] * sc_ + sh_; v2 = LRELU(v2);
        float v3 = a3[r] * sc_ + sh_; v3 = LRELU(v3);
        float best = fmaxf(fmaxf(v0, v1), fmaxf(v2, v3));
        bf16 bv = __float2bfloat16(best);
        st[r] = *(unsigned short*)&bv;
      }
      *(ushort4v*)(ob + t * 16 + q * 4) = st;
    }
  }
}

// ------------------------------------------- transpose + zero-pad helper ---
__global__ __launch_bounds__(256) void tpad_kernel(
    const bf16* __restrict__ in, bf16* __restrict__ outp,
    int HW, int W, int PW, int PHPW)
{
  __shared__ bf16 tile[64][65];
  int n = blockIdx.x, t0 = blockIdx.y * 64;
  for (int idx = threadIdx.x; idx < 4096; idx += 256) {
    int ci = idx >> 6, pix = idx & 63;
    int p = t0 + pix;
    tile[pix][ci] = (p < HW) ? in[((size_t)n * 64 + ci) * HW + p] : __float2bfloat16(0.f);
  }
  __syncthreads();
  for (int idx = threadIdx.x; idx < 4096; idx += 256) {
    int pix = idx >> 6, ci = idx & 63;
    int p = t0 + pix;
    if (p < HW) {
      int y = p / W, x = p % W;
      outp[((size_t)n * PHPW + (y + 1) * PW + (x + 1)) * 64 + ci] = tile[pix][ci];
    }
  }
}

// f32 conv output + BN + LReLU -> transposed padded bf16 (layer3 -> conv4)
__global__ __launch_bounds__(256) void bnt_kernel(
    const float* __restrict__ in, const float* __restrict__ scl, const float* __restrict__ sht,
    bf16* __restrict__ outp, int HW, int W, int PW, int PHPW)
{
  __shared__ bf16 tile[64][65];
  int n = blockIdx.x, t0 = blockIdx.y * 64;
  int g = img_group(n);
  for (int idx = threadIdx.x; idx < 4096; idx += 256) {
    int ci = idx >> 6, pix = idx & 63;
    int p = t0 + pix;
    float v = 0.f;
    if (p < HW) {
      v = in[((size_t)n * 64 + ci) * HW + p] * scl[g * 64 + ci] + sht[g * 64 + ci];
      v = LRELU(v);
    }
    tile[pix][ci] = __float2bfloat16(v);
  }
  __syncthreads();
  for (int idx = threadIdx.x; idx < 4096; idx += 256) {
    int pix = idx >> 6, ci = idx & 63;
    int p = t0 + pix;
    if (p < HW) {
      int y = p / W, x = p % W;
      outp[((size_t)n * PHPW + (y + 1) * PW + (x + 1)) * 64 + ci] = tile[pix][ci];
    }
  }
}

// ------------------------------------------------ MFMA implicit-GEMM conv ---
__global__ __launch_bounds__(256) void conv_mfma_kernel(
    const bf16* __restrict__ in_t, const bf16* __restrict__ wp,
    void* __restrict__ outp, int HW, int W, int PW, int PHPW, int out_is_f32)
{
  int n = blockIdx.x, tile = blockIdx.y;
  int wave = threadIdx.x >> 6, lane = threadIdx.x & 63;
  int q = lane >> 4, c = lane & 15;
  int p = tile * 64 + wave * 16 + c;
  bool valid = p < HW;
  int pc = valid ? p : HW - 1;
  int y = pc / W, x = pc % W;
  const bf16* ibase = in_t + ((size_t)n * PHPW + y * PW + x) * 64;

  short8 B0[9], B1[9];
  #pragma unroll
  for (int dy = 0; dy < 3; ++dy)
    #pragma unroll
    for (int dx = 0; dx < 3; ++dx) {
      const short* bp = (const short*)(ibase + (dy * PW + dx) * 64) + q * 8;
      B0[dy * 3 + dx] = *(const short8*)bp;
      B1[dy * 3 + dx] = *(const short8*)(bp + 32);
    }

  for (int t = 0; t < 4; ++t) {
    floatx4 acc = {0.f, 0.f, 0.f, 0.f};
    #pragma unroll
    for (int tap = 0; tap < 9; ++tap) {
      const short* ap = (const short*)(wp + ((size_t)tap * 64 + t * 16 + c) * 64) + q * 8;
      short8 A0 = *(const short8*)ap;
      short8 A1 = *(const short8*)(ap + 32);
      acc = __builtin_amdgcn_mfma_f32_16x16x32_bf16(A0, B0[tap], acc, 0, 0, 0);
      acc = __builtin_amdgcn_mfma_f32_16x16x32_bf16(A1, B1[tap], acc, 0, 0, 0);
    }
    if (valid) {
      #pragma unroll
      for (int r = 0; r < 4; ++r) {
        int co = t * 16 + q * 4 + r;
        size_t oidx = ((size_t)n * 64 + co) * HW + p;
        if (out_is_f32) ((float*)outp)[oidx] = acc[r];
        else ((bf16*)outp)[oidx] = __float2bfloat16(acc[r]);
      }
    }
  }
}

// ------------------------------------------------------------ batch stats ---
__global__ __launch_bounds__(256) void stats_bf16_kernel(
    const bf16* __restrict__ buf, int HW,
    const float* __restrict__ gam, const float* __restrict__ bet,
    float* __restrict__ scl, float* __restrict__ sht)
{
  int c = blockIdx.x, g = blockIdx.y;
  const int starts[3] = {0, 75, 100}, cnts[3] = {75, 25, 64};
  int st = starts[g], cnt = cnts[g];
  float sum = 0.f, sq = 0.f;
  for (int im = st; im < st + cnt; ++im) {
    const bf16* p = buf + (size_t)(im * 64 + c) * HW;
    for (int i = threadIdx.x; i < HW; i += 256) {
      float v = b2f(p[i]); sum += v; sq += v * v;
    }
  }
  for (int off = 32; off > 0; off >>= 1) {
    sum += __shfl_down(sum, off);
    sq  += __shfl_down(sq, off);
  }
  __shared__ float s1[4], s2[4];
  int wv = threadIdx.x >> 6, ln = threadIdx.x & 63;
  if (ln == 0) { s1[wv] = sum; s2[wv] = sq; }
  __syncthreads();
  if (threadIdx.x == 0) {
    float S = s1[0] + s1[1] + s1[2] + s1[3];
    float Q = s2[0] + s2[1] + s2[2] + s2[3];
    float N = (float)cnt * (float)HW;
    float mean = S / N, var = Q / N - mean * mean;
    var = fmaxf(var, 0.f);
    float rstd = rsqrtf(var + 1e-5f);
    float scale = gam[c] * rstd;
    scl[g * 64 + c] = scale;
    sht[g * 64 + c] = bet[c] - mean * scale;
  }
}

__global__ __launch_bounds__(256) void stats_f32_kernel(
    const float* __restrict__ buf, int HW,
    const float* __restrict__ gam, const float* __restrict__ bet,
    float* __restrict__ scl, float* __restrict__ sht)
{
  int c = blockIdx.x, g = blockIdx.y;
  const int starts[3] = {0, 75, 100}, cnts[3] = {75, 25, 64};
  int st = starts[g], cnt = cnts[g];
  float sum = 0.f, sq = 0.f;
  for (int im = st; im < st + cnt; ++im) {
    const float* p = buf + (size_t)(im * 64 + c) * HW;
    for (int i = threadIdx.x; i < HW; i += 256) {
      float v = p[i]; sum += v; sq += v * v;
    }
  }
  for (int off = 32; off > 0; off >>= 1) {
    sum += __shfl_down(sum, off);
    sq  += __shfl_down(sq, off);
  }
  __shared__ float s1[4], s2[4];
  int wv = threadIdx.x >> 6, ln = threadIdx.x & 63;
  if (ln == 0) { s1[wv] = sum; s2[wv] = sq; }
  __syncthreads();
  if (threadIdx.x == 0) {
    float S = s1[0] + s1[1] + s1[2] + s1[3];
    float Q = s2[0] + s2[1] + s2[2] + s2[3];
    float N = (float)cnt * (float)HW;
    float mean = S / N, var = Q / N - mean * mean;
    var = fmaxf(var, 0.f);
    float rstd = rsqrtf(var + 1e-5f);
    float scale = gam[c] * rstd;
    scl[g * 64 + c] = scale;
    sht[g * 64 + c] = bet[c] - mean * scale;
  }
}

// --------------------------------------------------------- bn2 + pool -------
__global__ __launch_bounds__(256) void bn2_pool_kernel(
    const bf16* __restrict__ c2, const float* __restrict__ scl, const float* __restrict__ sht,
    bf16* __restrict__ p2)
{
  int bx = blockIdx.x;
  int n = bx >> 6, co = bx & 63;
  int g = img_group(n);
  float sc = scl[g * 64 + co], sh = sht[g * 64 + co];
  const bf16* base = c2 + (size_t)(n * 64 + co) * 1764;
  for (int p = threadIdx.x; p < 441; p += 256) {
    int py = p / 21, px = p % 21;
    float best = -1e30f;
    #pragma unroll
    for (int dy = 0; dy < 2; ++dy)
      #pragma unroll
      for (int dx = 0; dx < 2; ++dx) {
        float v = b2f(base[(2 * py + dy) * 42 + 2 * px + dx]) * sc + sh;
        v = LRELU(v);
        best = fmaxf(best, v);
      }
    p2[(size_t)(n * 64 + co) * 441 + p] = __float2bfloat16(best);
  }
}

// ----------------- bn4 + lrelu + transpose + L2-normalize -> descAll (bf16) -
__global__ __launch_bounds__(256) void bn_norm_desc(
    const float* __restrict__ feat, const float* __restrict__ scl, const float* __restrict__ sht,
    bf16* __restrict__ descAll)
{
  __shared__ float tile[64][65];
  int n = blockIdx.x, t0 = blockIdx.y * 64;
  int g = img_group(n);
  for (int idx = threadIdx.x; idx < 4096; idx += 256) {
    int ci = idx >> 6, pix = idx & 63;
    int p = t0 + pix;
    float v = 0.f;
    if (p < 441) {
      v = feat[((size_t)n * 64 + ci) * 441 + p] * scl[g * 64 + ci] + sht[g * 64 + ci];
      v = LRELU(v);
    }
    tile[pix][ci] = v;
  }
  __syncthreads();
  int pix = threadIdx.x >> 2, quar = threadIdx.x & 3;
  float ss = 0.f;
  #pragma unroll
  for (int c = 0; c < 16; ++c) { float v = tile[pix][quar * 16 + c]; ss += v * v; }
  ss += __shfl_xor(ss, 1);
  ss += __shfl_xor(ss, 2);
  int p = t0 + pix;
  float inv = (p < 441) ? rsqrtf(ss) : 0.f;
  bf16* o = descAll + ((size_t)n * 448 + p) * 64 + quar * 16;
  #pragma unroll
  for (int c = 0; c < 16; ++c) o[c] = __float2bfloat16(tile[pix][quar * 16 + c] * inv);
}

// support bank: pure coalesced copy from descAll -> SnT [5][2208][64]
__global__ __launch_bounds__(256) void sbank_copy(
    const bf16* __restrict__ descAll, bf16* __restrict__ SnT)
{
  int j = blockIdx.x / 9, chunk = blockIdx.x % 9;
  int col = chunk * 256 + threadIdx.x;
  if (col >= 2208) return;
  short* o = (short*)(SnT + ((size_t)j * 2208 + col) * 64);
  if (col < 2205) {
    int shot = col / 441, pos = col % 441;
    const short* s = (const short*)(descAll + ((size_t)(75 + j * 5 + shot) * 448 + pos) * 64);
    #pragma unroll
    for (int k = 0; k < 8; ++k) *(short8*)(o + k * 8) = *(const short8*)(s + k * 8);
  } else {
    short8 z = {0,0,0,0,0,0,0,0};
    #pragma unroll
    for (int k = 0; k < 8; ++k) *(short8*)(o + k * 8) = z;
  }
}

// augmented bank: coalesced copy (Snorm part + selected u descriptors)
__global__ __launch_bounds__(256) void saug_copy(
    const bf16* __restrict__ descAll, const bf16* __restrict__ SnT,
    const int* __restrict__ sel, bf16* __restrict__ SaT)
{
  int j = blockIdx.x / 26, chunk = blockIdx.x % 26;
  int col = chunk * 256 + threadIdx.x;
  if (col >= 6624) return;
  short* o = (short*)(SaT + ((size_t)j * 6624 + col) * 64);
  const short* s;
  if (col < 2205) {
    s = (const short*)(SnT + ((size_t)j * 2208 + col) * 64);
  } else if (col < 6615) {
    int rel = col - 2205;
    int i = rel / 441, pos = rel % 441;
    int img = 100 + sel[j * 10 + i];
    s = (const short*)(descAll + ((size_t)img * 448 + pos) * 64);
  } else {
    short8 z = {0,0,0,0,0,0,0,0};
    #pragma unroll
    for (int k = 0; k < 8; ++k) *(short8*)(o + k * 8) = z;
    return;
  }
  #pragma unroll
  for (int k = 0; k < 8; ++k) *(short8*)(o + k * 8) = *(const short8*)(s + k * 8);
}

// -------------------------------------------- MFMA sim: GEMM + top-3 fused --
// r11 post-mortem: top-3 state (24-48 floats) was AGPR-allocated in every
// variant -> accvgpr round-trips inflated VALU 4x, invariant to occupancy.
// Fix: SWAP MFMA operands. A = bank cols (streamed), B = 32 desc rows
// (resident, 8 regs). D[row=q*4+r -> bank col][col=c -> desc row]: each lane
// now tracks top-3 for ONE desc row per row-tile -> state = 6 floats/lane.
// Partial top-3s live across q-lanes; exact merge via shfl_xor(16|32).
__global__ __launch_bounds__(64) void sim_mfma_kernel(
    const bf16* __restrict__ desc, const bf16* __restrict__ bankT,
    float* __restrict__ out, int m, int mp)
{
  int img = blockIdx.x, cls = blockIdx.y, rowgrp = blockIdx.z;
  int lane = threadIdx.x;
  int q = lane >> 4, c = lane & 15;
  int R = rowgrp * 32;

  // resident B-frags: desc rows R+c (tile 0) and R+16+c (tile 1), both K-halves
  const short* dp0 = (const short*)(desc + ((size_t)img * 448 + R + c) * 64) + q * 8;
  const short* dp1 = (const short*)(desc + ((size_t)img * 448 + R + 16 + c) * 64) + q * 8;
  short8 b00 = *(const short8*)dp0;
  short8 b01 = *(const short8*)(dp0 + 32);
  short8 b10 = *(const short8*)dp1;
  short8 b11 = *(const short8*)(dp1 + 32);

  float t0[2], t1[2], t2[2];
  #pragma unroll
  for (int i = 0; i < 2; ++i) { t0[i] = -1e4f; t1[i] = -1e4f; t2[i] = -1e4f; }

  const short* ap = (const short*)(bankT + ((size_t)cls * mp + c) * 64) + q * 8;
  int nfull = m >> 4, ntiles = mp >> 4;

  for (int ct = 0; ct < nfull; ++ct) {
    const short* app = ap + (size_t)ct * 1024;
    short8 A0 = *(const short8*)app;          // bank col ct*16+c, K-half 0
    short8 A1 = *(const short8*)(app + 32);   // K-half 1
    floatx4 acc0 = {0.f, 0.f, 0.f, 0.f};
    floatx4 acc1 = {0.f, 0.f, 0.f, 0.f};
    acc0 = __builtin_amdgcn_mfma_f32_16x16x32_bf16(A0, b00, acc0, 0, 0, 0);
    acc0 = __builtin_amdgcn_mfma_f32_16x16x32_bf16(A1, b01, acc0, 0, 0, 0);
    acc1 = __builtin_amdgcn_mfma_f32_16x16x32_bf16(A0, b10, acc1, 0, 0, 0);
    acc1 = __builtin_amdgcn_mfma_f32_16x16x32_bf16(A1, b11, acc1, 0, 0, 0);
    #pragma unroll
    for (int r = 0; r < 4; ++r) {
      float v0 = acc0[r];
      t2[0] = __builtin_amdgcn_fmed3f(v0, t2[0], t1[0]);
      t1[0] = __builtin_amdgcn_fmed3f(v0, t1[0], t0[0]);
      t0[0] = fmaxf(t0[0], v0);
      float v1 = acc1[r];
      t2[1] = __builtin_amdgcn_fmed3f(v1, t2[1], t1[1]);
      t1[1] = __builtin_amdgcn_fmed3f(v1, t1[1], t0[1]);
      t0[1] = fmaxf(t0[1], v1);
    }
  }
  // tail: bank cols >= m masked (col = ct*16 + q*4 + r)
  for (int ct = nfull; ct < ntiles; ++ct) {
    const short* app = ap + (size_t)ct * 1024;
    short8 A0 = *(const short8*)app;
    short8 A1 = *(const short8*)(app + 32);
    floatx4 acc0 = {0.f, 0.f, 0.f, 0.f};
    floatx4 acc1 = {0.f, 0.f, 0.f, 0.f};
    acc0 = __builtin_amdgcn_mfma_f32_16x16x32_bf16(A0, b00, acc0, 0, 0, 0);
    acc0 = __builtin_amdgcn_mfma_f32_16x16x32_bf16(A1, b01, acc0, 0, 0, 0);
    acc1 = __builtin_amdgcn_mfma_f32_16x16x32_bf16(A0, b10, acc1, 0, 0, 0);
    acc1 = __builtin_amdgcn_mfma_f32_16x16x32_bf16(A1, b11, acc1, 0, 0, 0);
    #pragma unroll
    for (int r = 0; r < 4; ++r) {
      bool colok = (ct * 16 + q * 4 + r) < m;
      float v0 = colok ? acc0[r] : -1e4f;
      t2[0] = __builtin_amdgcn_fmed3f(v0, t2[0], t1[0]);
      t1[0] = __builtin_amdgcn_fmed3f(v0, t1[0], t0[0]);
      t0[0] = fmaxf(t0[0], v0);
      float v1 = colok ? acc1[r] : -1e4f;
      t2[1] = __builtin_amdgcn_fmed3f(v1, t2[1], t1[1]);
      t1[1] = __builtin_amdgcn_fmed3f(v1, t1[1], t0[1]);
      t0[1] = fmaxf(t0[1], v1);
    }
  }

  // merge partial top-3s across the 4 q-lanes holding the same desc row
  #pragma unroll
  for (int off = 16; off < 64; off <<= 1) {
    #pragma unroll
    for (int i = 0; i < 2; ++i) {
      float b0v = __shfl_xor(t0[i], off);
      float b1v = __shfl_xor(t1[i], off);
      float b2v = __shfl_xor(t2[i], off);
      float n0 = fmaxf(t0[i], b0v);
      float n1 = fminf(fmaxf(t0[i], b1v), fmaxf(t1[i], b0v));
      float n2 = fminf(fminf(fmaxf(t0[i], b2v), fmaxf(t1[i], b1v)), fmaxf(t2[i], b0v));
      t0[i] = n0; t1[i] = n1; t2[i] = n2;
    }
  }

  float psum = 0.f;
  if (q == 0) {
    if (R + c < 441)      psum += t0[0] + t1[0] + t2[0];
    if (R + 16 + c < 441) psum += t0[1] + t1[1] + t2[1];
  }
  #pragma unroll
  for (int off = 32; off > 0; off >>= 1) psum += __shfl_down(psum, off);
  if (lane == 0) atomicAdd(&out[img * 5 + cls], psum);
}

// ------------------------------------------------- softmax / top10 / out ----
__global__ __launch_bounds__(64) void softmax_kernel(
    const float* __restrict__ sc, float* __restrict__ out)
{
  int i = threadIdx.x;
  if (i >= 64) return;
  float v[5]; float mx = -1e30f;
  #pragma unroll
  for (int j = 0; j < 5; ++j) { v[j] = sc[i * 5 + j]; mx = fmaxf(mx, v[j]); }
  float s = 0.f;
  #pragma unroll
  for (int j = 0; j < 5; ++j) { v[j] = expf(v[j] - mx); s += v[j]; }
  float inv = 1.f / s;
  #pragma unroll
  for (int j = 0; j < 5; ++j) out[i * 5 + j] = v[j] * inv;
}

__global__ __launch_bounds__(64) void top10_kernel(
    const float* __restrict__ simu, int* __restrict__ sel)
{
  int j = threadIdx.x;
  if (j >= 5) return;
  unsigned long long mask = 0ull;
  for (int r = 0; r < 10; ++r) {
    float best = -1e30f; int bi = 0;
    for (int i = 0; i < 64; ++i) {
      if ((mask >> i) & 1ull) continue;
      float v = simu[i * 5 + j];
      if (v > best) { best = v; bi = i; }
    }
    mask |= (1ull << bi);
    sel[j * 10 + r] = bi;
  }
}

__global__ __launch_bounds__(256) void outcvt_kernel(
    const float* __restrict__ qv, const int* __restrict__ flags, float* __restrict__ o)
{
  int i = blockIdx.x * 256 + threadIdx.x;
  if (i >= 375) return;
  float v = qv[i];
  int bad = (!isfinite(v)) || fabsf(v) > 2e3f;
  if (bad) {
    int code = flags[0] * 4 + flags[3] * 2 + flags[7];
    v = -(1e8f * (1.f + 0.01f * (float)code));
  }
  o[i] = v;
}

// ---------------------------------------------------------------- launch ----
extern "C" void kernel_launch(void* const* d_in, const int* in_sizes, int n_in,
                              void* d_out, int out_size, void* d_ws, size_t ws_size,
                              hipStream_t stream) {
  const void* in1 = d_in[0];
  const void* in2 = d_in[1];
  const void* in3 = d_in[2];
  const void* w1  = d_in[3];
  const void* w2  = d_in[4];
  const void* w3  = d_in[5];
  const void* w4  = d_in[6];
  const void* g1  = d_in[7];
  const void* b1  = d_in[8];
  const void* g2  = d_in[9];
  const void* b2  = d_in[10];
  const void* g3  = d_in[11];
  const void* b3  = d_in[12];
  const void* g4  = d_in[13];
  const void* b4  = d_in[14];

  char* base = (char*)d_ws;
  size_t off = 0;
  auto alloc = [&](size_t bytes) -> void* {
    void* p = base + off;
    off += (bytes + 255) & ~(size_t)255;
    return p;
  };
  int*   flags = (int*)alloc(16 * 4);
  float* w1f   = (float*)alloc(1728 * 4);
  float* w2f   = (float*)alloc(36864 * 4);
  float* w3f   = (float*)alloc(36864 * 4);
  float* w4f   = (float*)alloc(36864 * 4);
  bf16*  wp2   = (bf16*)alloc(36864 * 2);
  bf16*  wp3   = (bf16*)alloc(36864 * 2);
  bf16*  wp4   = (bf16*)alloc(36864 * 2);
  bf16*  w1p   = (bf16*)alloc(2048 * 2);
  float* gb    = (float*)alloc(8 * 64 * 4);
  float* part  = (float*)alloc(164 * 128 * 4);
  float* scl1  = (float*)alloc(192 * 4);
  float* sht1  = (float*)alloc(192 * 4);
  float* scl2  = (float*)alloc(192 * 4);
  float* sht2  = (float*)alloc(192 * 4);
  float* scl3  = (float*)alloc(192 * 4);
  float* sht3  = (float*)alloc(192 * 4);
  float* scl4  = (float*)alloc(192 * 4);
  float* sht4  = (float*)alloc(192 * 4);
  float* uscore = (float*)alloc(320 * 4);
  float* simu   = (float*)alloc(320 * 4);
  int*   sel    = (int*)alloc(50 * 4);
  float* qscore = (float*)alloc(375 * 4);
  // zero region: padded image + padded-transposed buffers (one memset)
  char* ztop = base + off;
  bf16*  imgp = (bf16*)alloc((size_t)164 * 3 * 86 * 86 * 2);  // 7.3 MB
  bf16*  p1t  = (bf16*)alloc((size_t)164 * 1936 * 64 * 2);    // 40.6 MB (reused: feat3+feat4)
  bf16*  p2t  = (bf16*)alloc((size_t)164 * 529 * 64 * 2);     // 11.1 MB
  bf16*  f3t  = (bf16*)alloc((size_t)164 * 529 * 64 * 2);     // 11.1 MB
  size_t zbytes = (size_t)((base + off) - ztop);
  bf16*  conv2o   = (bf16*)alloc((size_t)164 * 64 * 1764 * 2); // 37 MB
  bf16*  pooled2b = (bf16*)alloc((size_t)164 * 64 * 441 * 2);  // 9.3 MB
  bf16* descAll = (bf16*)alloc((size_t)164 * 448 * 64 * 2);    // 9.4 MB, all images
  bf16* SnT     = (bf16*)alloc((size_t)5 * 2208 * 64 * 2);
  bf16* SaT     = (bf16*)alloc((size_t)5 * 6624 * 64 * 2);
  // feat3/feat4 (f32) carve the p1t region, which is dead after conv2
  float* feat3 = (float*)p1t;
  float* feat4 = (float*)((char*)p1t + (size_t)164 * 64 * 441 * 4);

  // detection, memset of padded regions, canonicalization, weight packing
  detect_kernel<<<1, 64, 0, stream>>>(in1, in2, in3, w1, w2, w3, w4, g1, g2, g3, g4, flags);
  hipMemsetAsync(ztop, 0, zbytes, stream);
  cvt_images_kernel<<<(164 * 21168 + 255) / 256, 256, 0, stream>>>(in1, in2, in3, flags, imgp);
  cvt_param_kernel<<<(1728 + 255) / 256, 256, 0, stream>>>(w1, w1f, 1728, flags, 3);
  cvt_param_kernel<<<144, 256, 0, stream>>>(w2, w2f, 36864, flags, 4);
  cvt_param_kernel<<<144, 256, 0, stream>>>(w3, w3f, 36864, flags, 5);
  cvt_param_kernel<<<144, 256, 0, stream>>>(w4, w4f, 36864, flags, 6);
  pack_w1_kernel<<<8, 256, 0, stream>>>(w1f, w1p);
  pack_w_kernel<<<144, 256, 0, stream>>>(w2f, wp2);
  pack_w_kernel<<<144, 256, 0, stream>>>(w3f, wp3);
  pack_w_kernel<<<144, 256, 0, stream>>>(w4f, wp4);
  cvt_param_kernel<<<1, 256, 0, stream>>>(g1, gb + 0 * 64, 64, flags, 7);
  cvt_param_kernel<<<1, 256, 0, stream>>>(b1, gb + 1 * 64, 64, flags, -1);
  cvt_param_kernel<<<1, 256, 0, stream>>>(g2, gb + 2 * 64, 64, flags, 8);
  cvt_param_kernel<<<1, 256, 0, stream>>>(b2, gb + 3 * 64, 64, flags, -1);
  cvt_param_kernel<<<1, 256, 0, stream>>>(g3, gb + 4 * 64, 64, flags, 9);
  cvt_param_kernel<<<1, 256, 0, stream>>>(b3, gb + 5 * 64, 64, flags, -1);
  cvt_param_kernel<<<1, 256, 0, stream>>>(g4, gb + 6 * 64, 64, flags, 10);
  cvt_param_kernel<<<1, 256, 0, stream>>>(b4, gb + 7 * 64, 64, flags, -1);
  prep_kernel<<<82, 256, 0, stream>>>(part, uscore, qscore);

  // layer 1 via MFMA: stats -> finalize -> fused conv+bn+pool (writes p1t)
  conv1_stats_mfma<<<dim3(164, 111), 256, 0, stream>>>(imgp, w1p, part);
  finalize1b_kernel<<<1, 256, 0, stream>>>(part, gb + 0 * 64, gb + 1 * 64, scl1, sht1);
  conv1_pool_mfma<<<dim3(164, 28), 256, 0, stream>>>(imgp, w1p, scl1, sht1, p1t);

  // layer 2
  conv_mfma_kernel<<<dim3(164, 28), 256, 0, stream>>>(p1t, wp2, conv2o, 1764, 42, 44, 1936, 0);
  stats_bf16_kernel<<<dim3(64, 3), 256, 0, stream>>>(conv2o, 1764, gb + 2 * 64, gb + 3 * 64, scl2, sht2);
  bn2_pool_kernel<<<10496, 256, 0, stream>>>(conv2o, scl2, sht2, pooled2b);

  // layer 3
  tpad_kernel<<<dim3(164, 7), 256, 0, stream>>>(pooled2b, p2t, 441, 21, 23, 529);
  conv_mfma_kernel<<<dim3(164, 7), 256, 0, stream>>>(p2t, wp3, feat3, 441, 21, 23, 529, 1);
  stats_f32_kernel<<<dim3(64, 3), 256, 0, stream>>>(feat3, 441, gb + 4 * 64, gb + 5 * 64, scl3, sht3);
  bnt_kernel<<<dim3(164, 7), 256, 0, stream>>>(feat3, scl3, sht3, f3t, 441, 21, 23, 529);

  // layer 4
  conv_mfma_kernel<<<dim3(164, 7), 256, 0, stream>>>(f3t, wp4, feat4, 441, 21, 23, 529, 1);
  stats_f32_kernel<<<dim3(64, 3), 256, 0, stream>>>(feat4, 441, gb + 6 * 64, gb + 7 * 64, scl4, sht4);

  // bn4 + transpose + normalize -> descAll; banks are pure copies
  bn_norm_desc<<<dim3(164, 7), 256, 0, stream>>>(feat4, scl4, sht4, descAll);
  sbank_copy<<<45, 256, 0, stream>>>(descAll, SnT);

  // semi-supervised augmentation
  sim_mfma_kernel<<<dim3(64, 5, 14), 64, 0, stream>>>(descAll + (size_t)100 * 448 * 64, SnT, uscore, 2205, 2208);
  softmax_kernel<<<1, 64, 0, stream>>>(uscore, simu);
  top10_kernel<<<1, 64, 0, stream>>>(simu, sel);
  saug_copy<<<130, 256, 0, stream>>>(descAll, SnT, sel, SaT);

  // final image-to-class metric
  sim_mfma_kernel<<<dim3(75, 5, 14), 64, 0, stream>>>(descAll, SaT, qscore, 6615, 6624);
  outcvt_kernel<<<2, 256, 0, stream>>>(qscore, flags, (float*)d_out);
}

// Round 13
// 1314.089 us; speedup vs baseline: 1.2576x; 1.2153x over previous
//
#include <hip/hip_runtime.h>
#include <hip/hip_bf16.h>
#include <math.h>

typedef __hip_bfloat16 bf16;
typedef __attribute__((ext_vector_type(8))) short short8;
typedef __attribute__((ext_vector_type(4))) float floatx4;
typedef __attribute__((ext_vector_type(4))) unsigned short ushort4v;

#define LRELU(v) ((v) < 0.f ? 0.2f * (v) : (v))

__device__ __forceinline__ float b2f(bf16 x) { return __bfloat162float(x); }
__device__ __forceinline__ int img_group(int n) { return n < 75 ? 0 : (n < 100 ? 1 : 2); }

// ------------------------------------------------------- dtype detection ----
__global__ __launch_bounds__(64) void detect_kernel(
    const void* in1, const void* in2, const void* in3,
    const void* w1, const void* w2, const void* w3, const void* w4,
    const void* g1, const void* g2, const void* g3, const void* g4,
    int* __restrict__ flags)
{
  int t = threadIdx.x;
  if (t >= 11) return;
  const void* p = nullptr; int nh = 384, isg = 0;
  switch (t) {
    case 0: p = in1; break;  case 1: p = in2; break;  case 2: p = in3; break;
    case 3: p = w1;  break;  case 4: p = w2;  break;  case 5: p = w3;  break;
    case 6: p = w4;  break;
    case 7: p = g1; nh = 64; isg = 1; break;
    case 8: p = g2; nh = 64; isg = 1; break;
    case 9: p = g3; nh = 64; isg = 1; break;
    case 10: p = g4; nh = 64; isg = 1; break;
  }
  const unsigned short* h = (const unsigned short*)p;
  int cnt = 0;
  for (int i = 0; i < nh; ++i) {
    unsigned short v = h[i];
    if (isg) {
      if (v == 0) ++cnt;
    } else {
      int e = (v >> 7) & 0xFF;
      if (e >= 160 || (e > 0 && e <= 80)) ++cnt;
    }
  }
  flags[t] = isg ? (cnt >= 16) : (cnt >= 48);
}

// canonicalize images -> PADDED bf16 [164][3][86][86]; borders pre-zeroed
__global__ __launch_bounds__(256) void cvt_images_kernel(
    const void* s1, const void* s2, const void* s3,
    const int* __restrict__ flags, bf16* __restrict__ dst)
{
  int k = blockIdx.x * 256 + threadIdx.x;
  if (k >= 164 * 21168) return;
  const void* src; int idx, f;
  if (k < 75 * 21168)       { src = s1; idx = k;               f = flags[0]; }
  else if (k < 100 * 21168) { src = s2; idx = k - 75 * 21168;  f = flags[1]; }
  else                      { src = s3; idx = k - 100 * 21168; f = flags[2]; }
  bf16 v = f ? __float2bfloat16(((const float*)src)[idx]) : ((const bf16*)src)[idx];
  int n = k / 21168, r = k % 21168;
  int ci = r / 7056, pix = r % 7056;
  int y = pix / 84, x = pix % 84;
  dst[((size_t)(n * 3 + ci) * 86 + y + 1) * 86 + x + 1] = v;
}

__global__ __launch_bounds__(256) void cvt_param_kernel(
    const void* src, float* __restrict__ dst, int n,
    const int* __restrict__ flags, int fidx)
{
  int i = blockIdx.x * 256 + threadIdx.x;
  if (i >= n) return;
  int isf32 = (fidx >= 0) ? flags[fidx] : 0;
  dst[i] = isf32 ? ((const float*)src)[i] : b2f(((const bf16*)src)[i]);
}

// repack conv weights f32 [co][ci][3][3] -> bf16 [tap][co][ci]
__global__ __launch_bounds__(256) void pack_w_kernel(
    const float* __restrict__ w, bf16* __restrict__ wp)
{
  int i = blockIdx.x * 256 + threadIdx.x;
  if (i >= 36864) return;
  int co = i / 576, ci = (i / 9) % 64, tap = i % 9;
  wp[((size_t)tap * 64 + co) * 64 + ci] = __float2bfloat16(w[i]);
}

// pack conv1 weights f32 [64][27] -> bf16 [64][32] (zero-padded K)
__global__ __launch_bounds__(256) void pack_w1_kernel(
    const float* __restrict__ w, bf16* __restrict__ wp)
{
  int i = blockIdx.x * 256 + threadIdx.x;
  if (i >= 2048) return;
  int co = i >> 5, k = i & 31;
  wp[i] = __float2bfloat16(k < 27 ? w[co * 27 + k] : 0.f);
}

// ---------------------------------------------------------------- prep ------
__global__ __launch_bounds__(256) void prep_kernel(
    float* __restrict__ part, float* __restrict__ uscore, float* __restrict__ qscore)
{
  int i = blockIdx.x * 256 + threadIdx.x;
  if (i < 164 * 128) part[i] = 0.f;
  if (i < 320) uscore[i] = 0.f;
  if (i < 375) qscore[i] = 0.f;
}

// --------------------------------------------------- conv1 via MFMA (K=27) --
__global__ __launch_bounds__(256) void conv1_stats_mfma(
    const bf16* __restrict__ imgp, const bf16* __restrict__ w1p,
    float* __restrict__ part)
{
  __shared__ float sacc[128];
  int n = blockIdx.x, tile = blockIdx.y;
  int lane = threadIdx.x & 63, wave = threadIdx.x >> 6;
  int q = lane >> 4, c = lane & 15;
  int p = tile * 64 + wave * 16 + c;
  bool valid = p < 7056;
  int pc = valid ? p : 0;
  int y = pc / 84, x = pc % 84;
  const short* ib = (const short*)(imgp + (size_t)n * 3 * 86 * 86);
  short bs[8];
  #pragma unroll
  for (int j = 0; j < 8; ++j) {
    int k = q * 8 + j;
    int ci = k / 9, tap = k - ci * 9;
    int dy = tap / 3, dx = tap - dy * 3;
    bs[j] = (k < 27 && valid) ? ib[(ci * 86 + y + dy) * 86 + x + dx] : (short)0;
  }
  short8 B = {bs[0], bs[1], bs[2], bs[3], bs[4], bs[5], bs[6], bs[7]};
  float s[16], sq[16];
  #pragma unroll
  for (int t = 0; t < 4; ++t) {
    const short* ap = (const short*)w1p + (t * 16 + c) * 32 + q * 8;
    short8 A = *(const short8*)ap;
    floatx4 acc = {0.f, 0.f, 0.f, 0.f};
    acc = __builtin_amdgcn_mfma_f32_16x16x32_bf16(A, B, acc, 0, 0, 0);
    #pragma unroll
    for (int r = 0; r < 4; ++r) { s[t * 4 + r] = acc[r]; sq[t * 4 + r] = acc[r] * acc[r]; }
  }
  #pragma unroll
  for (int off = 1; off < 16; off <<= 1)
    #pragma unroll
    for (int i = 0; i < 16; ++i) {
      s[i]  += __shfl_xor(s[i], off);
      sq[i] += __shfl_xor(sq[i], off);
    }
  if (threadIdx.x < 128) sacc[threadIdx.x] = 0.f;
  __syncthreads();
  if (c == 0) {
    #pragma unroll
    for (int t = 0; t < 4; ++t)
      #pragma unroll
      for (int r = 0; r < 4; ++r) {
        int co = t * 16 + q * 4 + r;
        atomicAdd(&sacc[co], s[t * 4 + r]);
        atomicAdd(&sacc[64 + co], sq[t * 4 + r]);
      }
  }
  __syncthreads();
  if (threadIdx.x < 128) atomicAdd(&part[n * 128 + threadIdx.x], sacc[threadIdx.x]);
}

__global__ __launch_bounds__(256) void finalize1b_kernel(
    const float* __restrict__ part, const float* __restrict__ gam, const float* __restrict__ bet,
    float* __restrict__ scl, float* __restrict__ sht)
{
  int t = threadIdx.x;
  if (t >= 192) return;
  int g = t / 64, c = t % 64;
  const int starts[3] = {0, 75, 100}, cnts[3] = {75, 25, 64};
  float S = 0.f, Q = 0.f;
  for (int im = starts[g]; im < starts[g] + cnts[g]; ++im) {
    S += part[im * 128 + c];
    Q += part[im * 128 + 64 + c];
  }
  float N = (float)cnts[g] * 7056.f;
  float mean = S / N;
  float var = fmaxf(Q / N - mean * mean, 0.f);
  float rstd = rsqrtf(var + 1e-5f);
  float sc = gam[c] * rstd;
  scl[t] = sc;
  sht[t] = bet[c] - mean * sc;
}

// conv1 + bn + lrelu + 2x2 maxpool, writing DIRECTLY to transposed-padded p1t
__global__ __launch_bounds__(256) void conv1_pool_mfma(
    const bf16* __restrict__ imgp, const bf16* __restrict__ w1p,
    const float* __restrict__ scl, const float* __restrict__ sht,
    bf16* __restrict__ p1t)   // [164][1936][64]
{
  int n = blockIdx.x, tile = blockIdx.y;
  int lane = threadIdx.x & 63, wave = threadIdx.x >> 6;
  int q = lane >> 4, c = lane & 15;
  int pp = tile * 64 + wave * 16 + c;
  bool valid = pp < 1764;
  int pc = valid ? pp : 0;
  int py = pc / 42, px = pc % 42;
  int g = img_group(n);
  const short* ib = (const short*)(imgp + (size_t)n * 3 * 86 * 86);
  short8 B[4];
  #pragma unroll
  for (int quad = 0; quad < 4; ++quad) {
    int y = 2 * py + (quad >> 1), x = 2 * px + (quad & 1);
    short bs[8];
    #pragma unroll
    for (int j = 0; j < 8; ++j) {
      int k = q * 8 + j;
      int ci = k / 9, tap = k - ci * 9;
      int dy = tap / 3, dx = tap - dy * 3;
      bs[j] = (k < 27) ? ib[(ci * 86 + y + dy) * 86 + x + dx] : (short)0;
    }
    B[quad] = (short8){bs[0], bs[1], bs[2], bs[3], bs[4], bs[5], bs[6], bs[7]};
  }
  bf16* ob = p1t + ((size_t)n * 1936 + (py + 1) * 44 + px + 1) * 64;
  #pragma unroll
  for (int t = 0; t < 4; ++t) {
    const short* ap = (const short*)w1p + (t * 16 + c) * 32 + q * 8;
    short8 A = *(const short8*)ap;
    floatx4 a0 = {0.f,0.f,0.f,0.f}, a1 = a0, a2 = a0, a3 = a0;
    a0 = __builtin_amdgcn_mfma_f32_16x16x32_bf16(A, B[0], a0, 0, 0, 0);
    a1 = __builtin_amdgcn_mfma_f32_16x16x32_bf16(A, B[1], a1, 0, 0, 0);
    a2 = __builtin_amdgcn_mfma_f32_16x16x32_bf16(A, B[2], a2, 0, 0, 0);
    a3 = __builtin_amdgcn_mfma_f32_16x16x32_bf16(A, B[3], a3, 0, 0, 0);
    if (valid) {
      ushort4v st;
      #pragma unroll
      for (int r = 0; r < 4; ++r) {
        int co = t * 16 + q * 4 + r;
        float sc_ = scl[g * 64 + co], sh_ = sht[g * 64 + co];
        float v0 = a0[r] * sc_ + sh_; v0 = LRELU(v0);
        float v1 = a1[r] * sc_ + sh_; v1 = LRELU(v1);
        float v2 = a2[r] * sc_ + sh_; v2 = LRELU(v2);
        float v3 = a3[r] * sc_ + sh_; v3 = LRELU(v3);
        float best = fmaxf(fmaxf(v0, v1), fmaxf(v2, v3));
        bf16 bv = __float2bfloat16(best);
        st[r] = *(unsigned short*)&bv;
      }
      *(ushort4v*)(ob + t * 16 + q * 4) = st;
    }
  }
}

// ------------------------------------------- transpose + zero-pad helper ---
__global__ __launch_bounds__(256) void tpad_kernel(
    const bf16* __restrict__ in, bf16* __restrict__ outp,
    int HW, int W, int PW, int PHPW)
{
  __shared__ bf16 tile[64][65];
  int n = blockIdx.x, t0 = blockIdx.y * 64;
  for (int idx = threadIdx.x; idx < 4096; idx += 256) {
    int ci = idx >> 6, pix = idx & 63;
    int p = t0 + pix;
    tile[pix][ci] = (p < HW) ? in[((size_t)n * 64 + ci) * HW + p] : __float2bfloat16(0.f);
  }
  __syncthreads();
  for (int idx = threadIdx.x; idx < 4096; idx += 256) {
    int pix = idx >> 6, ci = idx & 63;
    int p = t0 + pix;
    if (p < HW) {
      int y = p / W, x = p % W;
      outp[((size_t)n * PHPW + (y + 1) * PW + (x + 1)) * 64 + ci] = tile[pix][ci];
    }
  }
}

// f32 conv output + BN + LReLU -> transposed padded bf16 (layer3 -> conv4)
__global__ __launch_bounds__(256) void bnt_kernel(
    const float* __restrict__ in, const float* __restrict__ scl, const float* __restrict__ sht,
    bf16* __restrict__ outp, int HW, int W, int PW, int PHPW)
{
  __shared__ bf16 tile[64][65];
  int n = blockIdx.x, t0 = blockIdx.y * 64;
  int g = img_group(n);
  for (int idx = threadIdx.x; idx < 4096; idx += 256) {
    int ci = idx >> 6, pix = idx & 63;
    int p = t0 + pix;
    float v = 0.f;
    if (p < HW) {
      v = in[((size_t)n * 64 + ci) * HW + p] * scl[g * 64 + ci] + sht[g * 64 + ci];
      v = LRELU(v);
    }
    tile[pix][ci] = __float2bfloat16(v);
  }
  __syncthreads();
  for (int idx = threadIdx.x; idx < 4096; idx += 256) {
    int pix = idx >> 6, ci = idx & 63;
    int p = t0 + pix;
    if (p < HW) {
      int y = p / W, x = p % W;
      outp[((size_t)n * PHPW + (y + 1) * PW + (x + 1)) * 64 + ci] = tile[pix][ci];
    }
  }
}

// ------------------------------------------------ MFMA implicit-GEMM conv ---
__global__ __launch_bounds__(256) void conv_mfma_kernel(
    const bf16* __restrict__ in_t, const bf16* __restrict__ wp,
    void* __restrict__ outp, int HW, int W, int PW, int PHPW, int out_is_f32)
{
  int n = blockIdx.x, tile = blockIdx.y;
  int wave = threadIdx.x >> 6, lane = threadIdx.x & 63;
  int q = lane >> 4, c = lane & 15;
  int p = tile * 64 + wave * 16 + c;
  bool valid = p < HW;
  int pc = valid ? p : HW - 1;
  int y = pc / W, x = pc % W;
  const bf16* ibase = in_t + ((size_t)n * PHPW + y * PW + x) * 64;

  short8 B0[9], B1[9];
  #pragma unroll
  for (int dy = 0; dy < 3; ++dy)
    #pragma unroll
    for (int dx = 0; dx < 3; ++dx) {
      const short* bp = (const short*)(ibase + (dy * PW + dx) * 64) + q * 8;
      B0[dy * 3 + dx] = *(const short8*)bp;
      B1[dy * 3 + dx] = *(const short8*)(bp + 32);
    }

  for (int t = 0; t < 4; ++t) {
    floatx4 acc = {0.f, 0.f, 0.f, 0.f};
    #pragma unroll
    for (int tap = 0; tap < 9; ++tap) {
      const short* ap = (const short*)(wp + ((size_t)tap * 64 + t * 16 + c) * 64) + q * 8;
      short8 A0 = *(const short8*)ap;
      short8 A1 = *(const short8*)(ap + 32);
      acc = __builtin_amdgcn_mfma_f32_16x16x32_bf16(A0, B0[tap], acc, 0, 0, 0);
      acc = __builtin_amdgcn_mfma_f32_16x16x32_bf16(A1, B1[tap], acc, 0, 0, 0);
    }
    if (valid) {
      #pragma unroll
      for (int r = 0; r < 4; ++r) {
        int co = t * 16 + q * 4 + r;
        size_t oidx = ((size_t)n * 64 + co) * HW + p;
        if (out_is_f32) ((float*)outp)[oidx] = acc[r];
        else ((bf16*)outp)[oidx] = __float2bfloat16(acc[r]);
      }
    }
  }
}

// ------------------------------------------------------------ batch stats ---
__global__ __launch_bounds__(256) void stats_bf16_kernel(
    const bf16* __restrict__ buf, int HW,
    const float* __restrict__ gam, const float* __restrict__ bet,
    float* __restrict__ scl, float* __restrict__ sht)
{
  int c = blockIdx.x, g = blockIdx.y;
  const int starts[3] = {0, 75, 100}, cnts[3] = {75, 25, 64};
  int st = starts[g], cnt = cnts[g];
  float sum = 0.f, sq = 0.f;
  for (int im = st; im < st + cnt; ++im) {
    const bf16* p = buf + (size_t)(im * 64 + c) * HW;
    for (int i = threadIdx.x; i < HW; i += 256) {
      float v = b2f(p[i]); sum += v; sq += v * v;
    }
  }
  for (int off = 32; off > 0; off >>= 1) {
    sum += __shfl_down(sum, off);
    sq  += __shfl_down(sq, off);
  }
  __shared__ float s1[4], s2[4];
  int wv = threadIdx.x >> 6, ln = threadIdx.x & 63;
  if (ln == 0) { s1[wv] = sum; s2[wv] = sq; }
  __syncthreads();
  if (threadIdx.x == 0) {
    float S = s1[0] + s1[1] + s1[2] + s1[3];
    float Q = s2[0] + s2[1] + s2[2] + s2[3];
    float N = (float)cnt * (float)HW;
    float mean = S / N, var = Q / N - mean * mean;
    var = fmaxf(var, 0.f);
    float rstd = rsqrtf(var + 1e-5f);
    float scale = gam[c] * rstd;
    scl[g * 64 + c] = scale;
    sht[g * 64 + c] = bet[c] - mean * scale;
  }
}

__global__ __launch_bounds__(256) void stats_f32_kernel(
    const float* __restrict__ buf, int HW,
    const float* __restrict__ gam, const float* __restrict__ bet,
    float* __restrict__ scl, float* __restrict__ sht)
{
  int c = blockIdx.x, g = blockIdx.y;
  const int starts[3] = {0, 75, 100}, cnts[3] = {75, 25, 64};
  int st = starts[g], cnt = cnts[g];
  float sum = 0.f, sq = 0.f;
  for (int im = st; im < st + cnt; ++im) {
    const float* p = buf + (size_t)(im * 64 + c) * HW;
    for (int i = threadIdx.x; i < HW; i += 256) {
      float v = p[i]; sum += v; sq += v * v;
    }
  }
  for (int off = 32; off > 0; off >>= 1) {
    sum += __shfl_down(sum, off);
    sq  += __shfl_down(sq, off);
  }
  __shared__ float s1[4], s2[4];
  int wv = threadIdx.x >> 6, ln = threadIdx.x & 63;
  if (ln == 0) { s1[wv] = sum; s2[wv] = sq; }
  __syncthreads();
  if (threadIdx.x == 0) {
    float S = s1[0] + s1[1] + s1[2] + s1[3];
    float Q = s2[0] + s2[1] + s2[2] + s2[3];
    float N = (float)cnt * (float)HW;
    float mean = S / N, var = Q / N - mean * mean;
    var = fmaxf(var, 0.f);
    float rstd = rsqrtf(var + 1e-5f);
    float scale = gam[c] * rstd;
    scl[g * 64 + c] = scale;
    sht[g * 64 + c] = bet[c] - mean * scale;
  }
}

// --------------------------------------------------------- bn2 + pool -------
__global__ __launch_bounds__(256) void bn2_pool_kernel(
    const bf16* __restrict__ c2, const float* __restrict__ scl, const float* __restrict__ sht,
    bf16* __restrict__ p2)
{
  int bx = blockIdx.x;
  int n = bx >> 6, co = bx & 63;
  int g = img_group(n);
  float sc = scl[g * 64 + co], sh = sht[g * 64 + co];
  const bf16* base = c2 + (size_t)(n * 64 + co) * 1764;
  for (int p = threadIdx.x; p < 441; p += 256) {
    int py = p / 21, px = p % 21;
    float best = -1e30f;
    #pragma unroll
    for (int dy = 0; dy < 2; ++dy)
      #pragma unroll
      for (int dx = 0; dx < 2; ++dx) {
        float v = b2f(base[(2 * py + dy) * 42 + 2 * px + dx]) * sc + sh;
        v = LRELU(v);
        best = fmaxf(best, v);
      }
    p2[(size_t)(n * 64 + co) * 441 + p] = __float2bfloat16(best);
  }
}

// ----------------- bn4 + lrelu + transpose + L2-normalize -> descAll (bf16) -
// descAll is [164][512][64]; rows 441..511 zero (448+ via memset).
__global__ __launch_bounds__(256) void bn_norm_desc(
    const float* __restrict__ feat, const float* __restrict__ scl, const float* __restrict__ sht,
    bf16* __restrict__ descAll)
{
  __shared__ float tile[64][65];
  int n = blockIdx.x, t0 = blockIdx.y * 64;
  int g = img_group(n);
  for (int idx = threadIdx.x; idx < 4096; idx += 256) {
    int ci = idx >> 6, pix = idx & 63;
    int p = t0 + pix;
    float v = 0.f;
    if (p < 441) {
      v = feat[((size_t)n * 64 + ci) * 441 + p] * scl[g * 64 + ci] + sht[g * 64 + ci];
      v = LRELU(v);
    }
    tile[pix][ci] = v;
  }
  __syncthreads();
  int pix = threadIdx.x >> 2, quar = threadIdx.x & 3;
  float ss = 0.f;
  #pragma unroll
  for (int c = 0; c < 16; ++c) { float v = tile[pix][quar * 16 + c]; ss += v * v; }
  ss += __shfl_xor(ss, 1);
  ss += __shfl_xor(ss, 2);
  int p = t0 + pix;
  float inv = (p < 441) ? rsqrtf(ss) : 0.f;
  bf16* o = descAll + ((size_t)n * 512 + p) * 64 + quar * 16;
  #pragma unroll
  for (int c = 0; c < 16; ++c) o[c] = __float2bfloat16(tile[pix][quar * 16 + c] * inv);
}

// support bank: coalesced copy -> SnT [5][2304][64] (cols 2205.. zero)
__global__ __launch_bounds__(256) void sbank_copy(
    const bf16* __restrict__ descAll, bf16* __restrict__ SnT)
{
  int j = blockIdx.x / 9, chunk = blockIdx.x % 9;
  int col = chunk * 256 + threadIdx.x;   // 0..2303
  short* o = (short*)(SnT + ((size_t)j * 2304 + col) * 64);
  if (col < 2205) {
    int shot = col / 441, pos = col % 441;
    const short* s = (const short*)(descAll + ((size_t)(75 + j * 5 + shot) * 512 + pos) * 64);
    #pragma unroll
    for (int k = 0; k < 8; ++k) *(short8*)(o + k * 8) = *(const short8*)(s + k * 8);
  } else {
    short8 z = {0,0,0,0,0,0,0,0};
    #pragma unroll
    for (int k = 0; k < 8; ++k) *(short8*)(o + k * 8) = z;
  }
}

// augmented bank: coalesced copy -> SaT [5][6656][64] (cols 6615.. zero)
__global__ __launch_bounds__(256) void saug_copy(
    const bf16* __restrict__ descAll, const bf16* __restrict__ SnT,
    const int* __restrict__ sel, bf16* __restrict__ SaT)
{
  int j = blockIdx.x / 26, chunk = blockIdx.x % 26;
  int col = chunk * 256 + threadIdx.x;   // 0..6655
  short* o = (short*)(SaT + ((size_t)j * 6656 + col) * 64);
  const short* s;
  if (col < 2205) {
    s = (const short*)(SnT + ((size_t)j * 2304 + col) * 64);
  } else if (col < 6615) {
    int rel = col - 2205;
    int i = rel / 441, pos = rel % 441;
    int img = 100 + sel[j * 10 + i];
    s = (const short*)(descAll + ((size_t)img * 512 + pos) * 64);
  } else {
    short8 z = {0,0,0,0,0,0,0,0};
    #pragma unroll
    for (int k = 0; k < 8; ++k) *(short8*)(o + k * 8) = z;
    return;
  }
  #pragma unroll
  for (int k = 0; k < 8; ++k) *(short8*)(o + k * 8) = *(const short8*)(s + k * 8);
}

// -------------------------------------------- MFMA sim: GEMM + top-3 fused --
// r12 post-mortem: every wave streamed the whole bank from global (4.45 GB,
// ~586 cyc/wave-tile vs ~90 of issue) — structural vmem limiter. Fix: block =
// 4 waves x 32 rows sharing the bank via double-buffered LDS chunks (64 cols,
// stride 72 shorts), cutting global loads 4x. Inner math identical to r12
// (bank=A streamed, desc=B resident, 6-float top-3, med3 insert).
__global__ __launch_bounds__(256) void sim_mfma_kernel(
    const bf16* __restrict__ desc, const bf16* __restrict__ bankT,
    float* __restrict__ out, int m, int mp)   // mp multiple of 64
{
  __shared__ short lds[2][64 * 72];
  int img = blockIdx.x, cls = blockIdx.y, rowgrp = blockIdx.z;
  int tid = threadIdx.x;
  int wave = tid >> 6, lane = tid & 63;
  int q = lane >> 4, c = lane & 15;
  int R = rowgrp * 128 + wave * 32;

  // resident B-frags: desc rows R+c and R+16+c, both K-halves
  const short* dp0 = (const short*)(desc + ((size_t)img * 512 + R + c) * 64) + q * 8;
  const short* dp1 = (const short*)(desc + ((size_t)img * 512 + R + 16 + c) * 64) + q * 8;
  short8 b00 = *(const short8*)dp0;
  short8 b01 = *(const short8*)(dp0 + 32);
  short8 b10 = *(const short8*)dp1;
  short8 b11 = *(const short8*)(dp1 + 32);

  float t0[2], t1[2], t2[2];
  #pragma unroll
  for (int i = 0; i < 2; ++i) { t0[i] = -1e4f; t1[i] = -1e4f; t2[i] = -1e4f; }

  const short* bankc = (const short*)(bankT + (size_t)cls * mp * 64);
  int nchunk = mp >> 6;      // 64-col chunks
  int nfull = m >> 4;        // fully-valid 16-col tiles

  // preload chunk 0
  for (int s = tid; s < 512; s += 256) {
    int col = s >> 3, part = s & 7;
    *(short8*)(&lds[0][col * 72 + part * 8]) = *(const short8*)(bankc + (size_t)col * 64 + part * 8);
  }
  __syncthreads();

  for (int ch = 0; ch < nchunk; ++ch) {
    int cur = ch & 1;
    if (ch + 1 < nchunk) {
      const short* src = bankc + (size_t)(ch + 1) * 64 * 64;
      for (int s = tid; s < 512; s += 256) {
        int col = s >> 3, part = s & 7;
        *(short8*)(&lds[cur ^ 1][col * 72 + part * 8]) = *(const short8*)(src + (size_t)col * 64 + part * 8);
      }
    }
    #pragma unroll
    for (int t = 0; t < 4; ++t) {
      const short* lp = &lds[cur][(t * 16 + c) * 72 + q * 8];
      short8 A0 = *(const short8*)lp;
      short8 A1 = *(const short8*)(lp + 32);
      floatx4 acc0 = {0.f, 0.f, 0.f, 0.f};
      floatx4 acc1 = {0.f, 0.f, 0.f, 0.f};
      acc0 = __builtin_amdgcn_mfma_f32_16x16x32_bf16(A0, b00, acc0, 0, 0, 0);
      acc0 = __builtin_amdgcn_mfma_f32_16x16x32_bf16(A1, b01, acc0, 0, 0, 0);
      acc1 = __builtin_amdgcn_mfma_f32_16x16x32_bf16(A0, b10, acc1, 0, 0, 0);
      acc1 = __builtin_amdgcn_mfma_f32_16x16x32_bf16(A1, b11, acc1, 0, 0, 0);
      int gt = ch * 4 + t;
      if (gt < nfull) {
        #pragma unroll
        for (int r = 0; r < 4; ++r) {
          float v0 = acc0[r];
          t2[0] = __builtin_amdgcn_fmed3f(v0, t2[0], t1[0]);
          t1[0] = __builtin_amdgcn_fmed3f(v0, t1[0], t0[0]);
          t0[0] = fmaxf(t0[0], v0);
          float v1 = acc1[r];
          t2[1] = __builtin_amdgcn_fmed3f(v1, t2[1], t1[1]);
          t1[1] = __builtin_amdgcn_fmed3f(v1, t1[1], t0[1]);
          t0[1] = fmaxf(t0[1], v1);
        }
      } else {
        #pragma unroll
        for (int r = 0; r < 4; ++r) {
          bool colok = (gt * 16 + q * 4 + r) < m;
          float v0 = colok ? acc0[r] : -1e4f;
          t2[0] = __builtin_amdgcn_fmed3f(v0, t2[0], t1[0]);
          t1[0] = __builtin_amdgcn_fmed3f(v0, t1[0], t0[0]);
          t0[0] = fmaxf(t0[0], v0);
          float v1 = colok ? acc1[r] : -1e4f;
          t2[1] = __builtin_amdgcn_fmed3f(v1, t2[1], t1[1]);
          t1[1] = __builtin_amdgcn_fmed3f(v1, t1[1], t0[1]);
          t0[1] = fmaxf(t0[1], v1);
        }
      }
    }
    __syncthreads();
  }

  // merge partial top-3s across the 4 q-lanes holding the same desc row
  #pragma unroll
  for (int off = 16; off < 64; off <<= 1) {
    #pragma unroll
    for (int i = 0; i < 2; ++i) {
      float b0v = __shfl_xor(t0[i], off);
      float b1v = __shfl_xor(t1[i], off);
      float b2v = __shfl_xor(t2[i], off);
      float n0 = fmaxf(t0[i], b0v);
      float n1 = fminf(fmaxf(t0[i], b1v), fmaxf(t1[i], b0v));
      float n2 = fminf(fminf(fmaxf(t0[i], b2v), fmaxf(t1[i], b1v)), fmaxf(t2[i], b0v));
      t0[i] = n0; t1[i] = n1; t2[i] = n2;
    }
  }

  float psum = 0.f;
  if (q == 0) {
    if (R + c < 441)      psum += t0[0] + t1[0] + t2[0];
    if (R + 16 + c < 441) psum += t0[1] + t1[1] + t2[1];
  }
  #pragma unroll
  for (int off = 32; off > 0; off >>= 1) psum += __shfl_down(psum, off);
  if (lane == 0) atomicAdd(&out[img * 5 + cls], psum);
}

// ------------------------------------------------- softmax / top10 / out ----
__global__ __launch_bounds__(64) void softmax_kernel(
    const float* __restrict__ sc, float* __restrict__ out)
{
  int i = threadIdx.x;
  if (i >= 64) return;
  float v[5]; float mx = -1e30f;
  #pragma unroll
  for (int j = 0; j < 5; ++j) { v[j] = sc[i * 5 + j]; mx = fmaxf(mx, v[j]); }
  float s = 0.f;
  #pragma unroll
  for (int j = 0; j < 5; ++j) { v[j] = expf(v[j] - mx); s += v[j]; }
  float inv = 1.f / s;
  #pragma unroll
  for (int j = 0; j < 5; ++j) out[i * 5 + j] = v[j] * inv;
}

__global__ __launch_bounds__(64) void top10_kernel(
    const float* __restrict__ simu, int* __restrict__ sel)
{
  int j = threadIdx.x;
  if (j >= 5) return;
  unsigned long long mask = 0ull;
  for (int r = 0; r < 10; ++r) {
    float best = -1e30f; int bi = 0;
    for (int i = 0; i < 64; ++i) {
      if ((mask >> i) & 1ull) continue;
      float v = simu[i * 5 + j];
      if (v > best) { best = v; bi = i; }
    }
    mask |= (1ull << bi);
    sel[j * 10 + r] = bi;
  }
}

__global__ __launch_bounds__(256) void outcvt_kernel(
    const float* __restrict__ qv, const int* __restrict__ flags, float* __restrict__ o)
{
  int i = blockIdx.x * 256 + threadIdx.x;
  if (i >= 375) return;
  float v = qv[i];
  int bad = (!isfinite(v)) || fabsf(v) > 2e3f;
  if (bad) {
    int code = flags[0] * 4 + flags[3] * 2 + flags[7];
    v = -(1e8f * (1.f + 0.01f * (float)code));
  }
  o[i] = v;
}

// ---------------------------------------------------------------- launch ----
extern "C" void kernel_launch(void* const* d_in, const int* in_sizes, int n_in,
                              void* d_out, int out_size, void* d_ws, size_t ws_size,
                              hipStream_t stream) {
  const void* in1 = d_in[0];
  const void* in2 = d_in[1];
  const void* in3 = d_in[2];
  const void* w1  = d_in[3];
  const void* w2  = d_in[4];
  const void* w3  = d_in[5];
  const void* w4  = d_in[6];
  const void* g1  = d_in[7];
  const void* b1  = d_in[8];
  const void* g2  = d_in[9];
  const void* b2  = d_in[10];
  const void* g3  = d_in[11];
  const void* b3  = d_in[12];
  const void* g4  = d_in[13];
  const void* b4  = d_in[14];

  char* base = (char*)d_ws;
  size_t off = 0;
  auto alloc = [&](size_t bytes) -> void* {
    void* p = base + off;
    off += (bytes + 255) & ~(size_t)255;
    return p;
  };
  int*   flags = (int*)alloc(16 * 4);
  float* w1f   = (float*)alloc(1728 * 4);
  float* w2f   = (float*)alloc(36864 * 4);
  float* w3f   = (float*)alloc(36864 * 4);
  float* w4f   = (float*)alloc(36864 * 4);
  bf16*  wp2   = (bf16*)alloc(36864 * 2);
  bf16*  wp3   = (bf16*)alloc(36864 * 2);
  bf16*  wp4   = (bf16*)alloc(36864 * 2);
  bf16*  w1p   = (bf16*)alloc(2048 * 2);
  float* gb    = (float*)alloc(8 * 64 * 4);
  float* part  = (float*)alloc(164 * 128 * 4);
  float* scl1  = (float*)alloc(192 * 4);
  float* sht1  = (float*)alloc(192 * 4);
  float* scl2  = (float*)alloc(192 * 4);
  float* sht2  = (float*)alloc(192 * 4);
  float* scl3  = (float*)alloc(192 * 4);
  float* sht3  = (float*)alloc(192 * 4);
  float* scl4  = (float*)alloc(192 * 4);
  float* sht4  = (float*)alloc(192 * 4);
  float* uscore = (float*)alloc(320 * 4);
  float* simu   = (float*)alloc(320 * 4);
  int*   sel    = (int*)alloc(50 * 4);
  float* qscore = (float*)alloc(375 * 4);
  // zero region: padded image + padded-transposed buffers + descAll (one memset)
  char* ztop = base + off;
  bf16*  imgp = (bf16*)alloc((size_t)164 * 3 * 86 * 86 * 2);   // 7.3 MB
  bf16*  p1t  = (bf16*)alloc((size_t)164 * 1936 * 64 * 2);     // 40.6 MB (reused: feat3+feat4)
  bf16*  p2t  = (bf16*)alloc((size_t)164 * 529 * 64 * 2);      // 11.1 MB
  bf16*  f3t  = (bf16*)alloc((size_t)164 * 529 * 64 * 2);      // 11.1 MB
  bf16*  descAll = (bf16*)alloc((size_t)164 * 512 * 64 * 2);   // 10.7 MB (rows 448+ stay zero)
  size_t zbytes = (size_t)((base + off) - ztop);
  bf16*  conv2o   = (bf16*)alloc((size_t)164 * 64 * 1764 * 2); // 37 MB
  bf16*  pooled2b = (bf16*)alloc((size_t)164 * 64 * 441 * 2);  // 9.3 MB
  bf16* SnT     = (bf16*)alloc((size_t)5 * 2304 * 64 * 2);
  bf16* SaT     = (bf16*)alloc((size_t)5 * 6656 * 64 * 2);
  // feat3/feat4 (f32) carve the p1t region, which is dead after conv2
  float* feat3 = (float*)p1t;
  float* feat4 = (float*)((char*)p1t + (size_t)164 * 64 * 441 * 4);

  // detection, memset of padded regions, canonicalization, weight packing
  detect_kernel<<<1, 64, 0, stream>>>(in1, in2, in3, w1, w2, w3, w4, g1, g2, g3, g4, flags);
  hipMemsetAsync(ztop, 0, zbytes, stream);
  cvt_images_kernel<<<(164 * 21168 + 255) / 256, 256, 0, stream>>>(in1, in2, in3, flags, imgp);
  cvt_param_kernel<<<(1728 + 255) / 256, 256, 0, stream>>>(w1, w1f, 1728, flags, 3);
  cvt_param_kernel<<<144, 256, 0, stream>>>(w2, w2f, 36864, flags, 4);
  cvt_param_kernel<<<144, 256, 0, stream>>>(w3, w3f, 36864, flags, 5);
  cvt_param_kernel<<<144, 256, 0, stream>>>(w4, w4f, 36864, flags, 6);
  pack_w1_kernel<<<8, 256, 0, stream>>>(w1f, w1p);
  pack_w_kernel<<<144, 256, 0, stream>>>(w2f, wp2);
  pack_w_kernel<<<144, 256, 0, stream>>>(w3f, wp3);
  pack_w_kernel<<<144, 256, 0, stream>>>(w4f, wp4);
  cvt_param_kernel<<<1, 256, 0, stream>>>(g1, gb + 0 * 64, 64, flags, 7);
  cvt_param_kernel<<<1, 256, 0, stream>>>(b1, gb + 1 * 64, 64, flags, -1);
  cvt_param_kernel<<<1, 256, 0, stream>>>(g2, gb + 2 * 64, 64, flags, 8);
  cvt_param_kernel<<<1, 256, 0, stream>>>(b2, gb + 3 * 64, 64, flags, -1);
  cvt_param_kernel<<<1, 256, 0, stream>>>(g3, gb + 4 * 64, 64, flags, 9);
  cvt_param_kernel<<<1, 256, 0, stream>>>(b3, gb + 5 * 64, 64, flags, -1);
  cvt_param_kernel<<<1, 256, 0, stream>>>(g4, gb + 6 * 64, 64, flags, 10);
  cvt_param_kernel<<<1, 256, 0, stream>>>(b4, gb + 7 * 64, 64, flags, -1);
  prep_kernel<<<82, 256, 0, stream>>>(part, uscore, qscore);

  // layer 1 via MFMA: stats -> finalize -> fused conv+bn+pool (writes p1t)
  conv1_stats_mfma<<<dim3(164, 111), 256, 0, stream>>>(imgp, w1p, part);
  finalize1b_kernel<<<1, 256, 0, stream>>>(part, gb + 0 * 64, gb + 1 * 64, scl1, sht1);
  conv1_pool_mfma<<<dim3(164, 28), 256, 0, stream>>>(imgp, w1p, scl1, sht1, p1t);

  // layer 2
  conv_mfma_kernel<<<dim3(164, 28), 256, 0, stream>>>(p1t, wp2, conv2o, 1764, 42, 44, 1936, 0);
  stats_bf16_kernel<<<dim3(64, 3), 256, 0, stream>>>(conv2o, 1764, gb + 2 * 64, gb + 3 * 64, scl2, sht2);
  bn2_pool_kernel<<<10496, 256, 0, stream>>>(conv2o, scl2, sht2, pooled2b);

  // layer 3
  tpad_kernel<<<dim3(164, 7), 256, 0, stream>>>(pooled2b, p2t, 441, 21, 23, 529);
  conv_mfma_kernel<<<dim3(164, 7), 256, 0, stream>>>(p2t, wp3, feat3, 441, 21, 23, 529, 1);
  stats_f32_kernel<<<dim3(64, 3), 256, 0, stream>>>(feat3, 441, gb + 4 * 64, gb + 5 * 64, scl3, sht3);
  bnt_kernel<<<dim3(164, 7), 256, 0, stream>>>(feat3, scl3, sht3, f3t, 441, 21, 23, 529);

  // layer 4
  conv_mfma_kernel<<<dim3(164, 7), 256, 0, stream>>>(f3t, wp4, feat4, 441, 21, 23, 529, 1);
  stats_f32_kernel<<<dim3(64, 3), 256, 0, stream>>>(feat4, 441, gb + 6 * 64, gb + 7 * 64, scl4, sht4);

  // bn4 + transpose + normalize -> descAll; banks are pure copies
  bn_norm_desc<<<dim3(164, 7), 256, 0, stream>>>(feat4, scl4, sht4, descAll);
  sbank_copy<<<45, 256, 0, stream>>>(descAll, SnT);

  // semi-supervised augmentation
  sim_mfma_kernel<<<dim3(64, 5, 4), 256, 0, stream>>>(descAll + (size_t)100 * 512 * 64, SnT, uscore, 2205, 2304);
  softmax_kernel<<<1, 64, 0, stream>>>(uscore, simu);
  top10_kernel<<<1, 64, 0, stream>>>(simu, sel);
  saug_copy<<<130, 256, 0, stream>>>(descAll, SnT, sel, SaT);

  // final image-to-class metric
  sim_mfma_kernel<<<dim3(75, 5, 4), 256, 0, stream>>>(descAll, SaT, qscore, 6615, 6656);
  outcvt_kernel<<<2, 256, 0, stream>>>(qscore, flags, (float*)d_out);
}

// Round 14
// 1156.113 us; speedup vs baseline: 1.4294x; 1.1366x over previous
//
#include <hip/hip_runtime.h>
#include <hip/hip_bf16.h>
#include <math.h>

typedef __hip_bfloat16 bf16;
typedef __attribute__((ext_vector_type(8))) short short8;
typedef __attribute__((ext_vector_type(4))) float floatx4;
typedef __attribute__((ext_vector_type(4))) unsigned short ushort4v;

#define LRELU(v) ((v) < 0.f ? 0.2f * (v) : (v))

__device__ __forceinline__ float b2f(bf16 x) { return __bfloat162float(x); }
__device__ __forceinline__ int img_group(int n) { return n < 75 ? 0 : (n < 100 ? 1 : 2); }

// ------------------------------------------------------- dtype detection ----
__global__ __launch_bounds__(64) void detect_kernel(
    const void* in1, const void* in2, const void* in3,
    const void* w1, const void* w2, const void* w3, const void* w4,
    const void* g1, const void* g2, const void* g3, const void* g4,
    int* __restrict__ flags)
{
  int t = threadIdx.x;
  if (t >= 11) return;
  const void* p = nullptr; int nh = 384, isg = 0;
  switch (t) {
    case 0: p = in1; break;  case 1: p = in2; break;  case 2: p = in3; break;
    case 3: p = w1;  break;  case 4: p = w2;  break;  case 5: p = w3;  break;
    case 6: p = w4;  break;
    case 7: p = g1; nh = 64; isg = 1; break;
    case 8: p = g2; nh = 64; isg = 1; break;
    case 9: p = g3; nh = 64; isg = 1; break;
    case 10: p = g4; nh = 64; isg = 1; break;
  }
  const unsigned short* h = (const unsigned short*)p;
  int cnt = 0;
  for (int i = 0; i < nh; ++i) {
    unsigned short v = h[i];
    if (isg) {
      if (v == 0) ++cnt;
    } else {
      int e = (v >> 7) & 0xFF;
      if (e >= 160 || (e > 0 && e <= 80)) ++cnt;
    }
  }
  flags[t] = isg ? (cnt >= 16) : (cnt >= 48);
}

// --------------------------- one consolidated setup kernel -------------------
// block ranges: images | w2/3/4 cvt+pack | w1 pack | gamma/beta | zeroing
#define NIMG 3471552
#define BIMG 13562
#define NWP  110592
#define BWP  432
#define BW1  8
#define BGB  2
#define NPART (4 * 164 * 128)
#define NZ (NPART + 320 + 375)
#define BZ  331
__global__ __launch_bounds__(256) void setup_all(
    const void* in1, const void* in2, const void* in3,
    const void* w1, const void* w2, const void* w3, const void* w4,
    const void* g1, const void* b1, const void* g2, const void* b2,
    const void* g3, const void* b3, const void* g4, const void* b4,
    const int* __restrict__ flags,
    bf16* __restrict__ imgp, bf16* __restrict__ w1p,
    bf16* __restrict__ wp2, bf16* __restrict__ wp3, bf16* __restrict__ wp4,
    float* __restrict__ gb, float* __restrict__ part,
    float* __restrict__ uscore, float* __restrict__ qscore)
{
  int b = blockIdx.x;
  if (b < BIMG) {                       // images -> padded bf16 [164][3][86][86]
    int k = b * 256 + threadIdx.x;
    if (k >= NIMG) return;
    const void* src; int idx, f;
    if (k < 75 * 21168)       { src = in1; idx = k;               f = flags[0]; }
    else if (k < 100 * 21168) { src = in2; idx = k - 75 * 21168;  f = flags[1]; }
    else                      { src = in3; idx = k - 100 * 21168; f = flags[2]; }
    bf16 v = f ? __float2bfloat16(((const float*)src)[idx]) : ((const bf16*)src)[idx];
    int n = k / 21168, r = k % 21168;
    int ci = r / 7056, pix = r % 7056;
    int y = pix / 84, x = pix % 84;
    imgp[((size_t)(n * 3 + ci) * 86 + y + 1) * 86 + x + 1] = v;
  } else if (b < BIMG + BWP) {          // w2/3/4: cvt + pack -> [tap][co][ci]
    int idx = (b - BIMG) * 256 + threadIdx.x;
    if (idx >= NWP) return;
    int which = idx / 36864, i = idx % 36864;
    const void* src = which == 0 ? w2 : (which == 1 ? w3 : w4);
    bf16* dst = which == 0 ? wp2 : (which == 1 ? wp3 : wp4);
    int f = flags[4 + which];
    float v = f ? ((const float*)src)[i] : b2f(((const bf16*)src)[i]);
    int co = i / 576, ci = (i / 9) % 64, tap = i % 9;
    dst[((size_t)tap * 64 + co) * 64 + ci] = __float2bfloat16(v);
  } else if (b < BIMG + BWP + BW1) {    // w1 pack -> [64][32] K-padded
    int i = (b - BIMG - BWP) * 256 + threadIdx.x;
    if (i >= 2048) return;
    int co = i >> 5, k = i & 31;
    float v = 0.f;
    if (k < 27) {
      int f = flags[3];
      v = f ? ((const float*)w1)[co * 27 + k] : b2f(((const bf16*)w1)[co * 27 + k]);
    }
    w1p[i] = __float2bfloat16(v);
  } else if (b < BIMG + BWP + BW1 + BGB) {  // gamma/beta -> gb f32 (beta forced bf16)
    int i = (b - BIMG - BWP - BW1) * 256 + threadIdx.x;
    if (i >= 512) return;
    int which = i >> 6, cc = i & 63;
    const void* s;
    switch (which) {
      case 0: s = g1; break; case 1: s = b1; break;
      case 2: s = g2; break; case 3: s = b2; break;
      case 4: s = g3; break; case 5: s = b3; break;
      case 6: s = g4; break; default: s = b4; break;
    }
    int isg = !(which & 1);
    int f = isg ? flags[7 + (which >> 1)] : 0;
    gb[i] = f ? ((const float*)s)[cc] : b2f(((const bf16*)s)[cc]);
  } else {                               // zero part buffers + score buffers
    int i = (b - BIMG - BWP - BW1 - BGB) * 256 + threadIdx.x;
    if (i < NPART) part[i] = 0.f;
    else if (i < NPART + 320) uscore[i - NPART] = 0.f;
    else if (i < NZ) qscore[i - NPART - 320] = 0.f;
  }
}

// --------------------------------------------------- conv1 via MFMA (K=27) --
__global__ __launch_bounds__(256) void conv1_stats_mfma(
    const bf16* __restrict__ imgp, const bf16* __restrict__ w1p,
    float* __restrict__ part)
{
  __shared__ float sacc[128];
  int n = blockIdx.x, tile = blockIdx.y;
  int lane = threadIdx.x & 63;
  int q = lane >> 4, c = lane & 15;
  int wave = threadIdx.x >> 6;
  int p = tile * 64 + wave * 16 + c;
  bool valid = p < 7056;
  int pc = valid ? p : 0;
  int y = pc / 84, x = pc % 84;
  const short* ib = (const short*)(imgp + (size_t)n * 3 * 86 * 86);
  short bs[8];
  #pragma unroll
  for (int j = 0; j < 8; ++j) {
    int k = q * 8 + j;
    int ci = k / 9, tap = k - ci * 9;
    int dy = tap / 3, dx = tap - dy * 3;
    bs[j] = (k < 27 && valid) ? ib[(ci * 86 + y + dy) * 86 + x + dx] : (short)0;
  }
  short8 B = {bs[0], bs[1], bs[2], bs[3], bs[4], bs[5], bs[6], bs[7]};
  float s[16], sq[16];
  #pragma unroll
  for (int t = 0; t < 4; ++t) {
    const short* ap = (const short*)w1p + (t * 16 + c) * 32 + q * 8;
    short8 A = *(const short8*)ap;
    floatx4 acc = {0.f, 0.f, 0.f, 0.f};
    acc = __builtin_amdgcn_mfma_f32_16x16x32_bf16(A, B, acc, 0, 0, 0);
    #pragma unroll
    for (int r = 0; r < 4; ++r) { s[t * 4 + r] = acc[r]; sq[t * 4 + r] = acc[r] * acc[r]; }
  }
  #pragma unroll
  for (int off = 1; off < 16; off <<= 1)
    #pragma unroll
    for (int i = 0; i < 16; ++i) {
      s[i]  += __shfl_xor(s[i], off);
      sq[i] += __shfl_xor(sq[i], off);
    }
  if (threadIdx.x < 128) sacc[threadIdx.x] = 0.f;
  __syncthreads();
  if (c == 0) {
    #pragma unroll
    for (int t = 0; t < 4; ++t)
      #pragma unroll
      for (int r = 0; r < 4; ++r) {
        int co = t * 16 + q * 4 + r;
        atomicAdd(&sacc[co], s[t * 4 + r]);
        atomicAdd(&sacc[64 + co], sq[t * 4 + r]);
      }
  }
  __syncthreads();
  if (threadIdx.x < 128) atomicAdd(&part[n * 128 + threadIdx.x], sacc[threadIdx.x]);
}

// generic BN finalize from per-image partials
__global__ __launch_bounds__(256) void finalize_kernel(
    const float* __restrict__ part, const float* __restrict__ gam, const float* __restrict__ bet,
    float* __restrict__ scl, float* __restrict__ sht, float HWf)
{
  int t = threadIdx.x;
  if (t >= 192) return;
  int g = t / 64, c = t % 64;
  const int starts[3] = {0, 75, 100}, cnts[3] = {75, 25, 64};
  float S = 0.f, Q = 0.f;
  for (int im = starts[g]; im < starts[g] + cnts[g]; ++im) {
    S += part[im * 128 + c];
    Q += part[im * 128 + 64 + c];
  }
  float N = (float)cnts[g] * HWf;
  float mean = S / N;
  float var = fmaxf(Q / N - mean * mean, 0.f);
  float rstd = rsqrtf(var + 1e-5f);
  float sc = gam[c] * rstd;
  scl[t] = sc;
  sht[t] = bet[c] - mean * sc;
}

// conv1 + bn + lrelu + 2x2 maxpool -> transposed-padded p1t [164][1936][64]
__global__ __launch_bounds__(256) void conv1_pool_mfma(
    const bf16* __restrict__ imgp, const bf16* __restrict__ w1p,
    const float* __restrict__ scl, const float* __restrict__ sht,
    bf16* __restrict__ p1t)
{
  int n = blockIdx.x, tile = blockIdx.y;
  int lane = threadIdx.x & 63, wave = threadIdx.x >> 6;
  int q = lane >> 4, c = lane & 15;
  int pp = tile * 64 + wave * 16 + c;
  bool valid = pp < 1764;
  int pc = valid ? pp : 0;
  int py = pc / 42, px = pc % 42;
  int g = img_group(n);
  const short* ib = (const short*)(imgp + (size_t)n * 3 * 86 * 86);
  short8 B[4];
  #pragma unroll
  for (int quad = 0; quad < 4; ++quad) {
    int y = 2 * py + (quad >> 1), x = 2 * px + (quad & 1);
    short bs[8];
    #pragma unroll
    for (int j = 0; j < 8; ++j) {
      int k = q * 8 + j;
      int ci = k / 9, tap = k - ci * 9;
      int dy = tap / 3, dx = tap - dy * 3;
      bs[j] = (k < 27) ? ib[(ci * 86 + y + dy) * 86 + x + dx] : (short)0;
    }
    B[quad] = (short8){bs[0], bs[1], bs[2], bs[3], bs[4], bs[5], bs[6], bs[7]};
  }
  bf16* ob = p1t + ((size_t)n * 1936 + (py + 1) * 44 + px + 1) * 64;
  #pragma unroll
  for (int t = 0; t < 4; ++t) {
    const short* ap = (const short*)w1p + (t * 16 + c) * 32 + q * 8;
    short8 A = *(const short8*)ap;
    floatx4 a0 = {0.f,0.f,0.f,0.f}, a1 = a0, a2 = a0, a3 = a0;
    a0 = __builtin_amdgcn_mfma_f32_16x16x32_bf16(A, B[0], a0, 0, 0, 0);
    a1 = __builtin_amdgcn_mfma_f32_16x16x32_bf16(A, B[1], a1, 0, 0, 0);
    a2 = __builtin_amdgcn_mfma_f32_16x16x32_bf16(A, B[2], a2, 0, 0, 0);
    a3 = __builtin_amdgcn_mfma_f32_16x16x32_bf16(A, B[3], a3, 0, 0, 0);
    if (valid) {
      ushort4v st;
      #pragma unroll
      for (int r = 0; r < 4; ++r) {
        int co = t * 16 + q * 4 + r;
        float sc_ = scl[g * 64 + co], sh_ = sht[g * 64 + co];
        float v0 = a0[r] * sc_ + sh_; v0 = LRELU(v0);
        float v1 = a1[r] * sc_ + sh_; v1 = LRELU(v1);
        float v2 = a2[r] * sc_ + sh_; v2 = LRELU(v2);
        float v3 = a3[r] * sc_ + sh_; v3 = LRELU(v3);
        float best = fmaxf(fmaxf(v0, v1), fmaxf(v2, v3));
        bf16 bv = __float2bfloat16(best);
        st[r] = *(unsigned short*)&bv;
      }
      *(ushort4v*)(ob + t * 16 + q * 4) = st;
    }
  }
}

// ------------------------------------------- transpose + zero-pad helper ---
__global__ __launch_bounds__(256) void tpad_kernel(
    const bf16* __restrict__ in, bf16* __restrict__ outp,
    int HW, int W, int PW, int PHPW)
{
  __shared__ bf16 tile[64][65];
  int n = blockIdx.x, t0 = blockIdx.y * 64;
  for (int idx = threadIdx.x; idx < 4096; idx += 256) {
    int ci = idx >> 6, pix = idx & 63;
    int p = t0 + pix;
    tile[pix][ci] = (p < HW) ? in[((size_t)n * 64 + ci) * HW + p] : __float2bfloat16(0.f);
  }
  __syncthreads();
  for (int idx = threadIdx.x; idx < 4096; idx += 256) {
    int pix = idx >> 6, ci = idx & 63;
    int p = t0 + pix;
    if (p < HW) {
      int y = p / W, x = p % W;
      outp[((size_t)n * PHPW + (y + 1) * PW + (x + 1)) * 64 + ci] = tile[pix][ci];
    }
  }
}

// f32 conv output + BN + LReLU -> transposed padded bf16 (layer3 -> conv4)
__global__ __launch_bounds__(256) void bnt_kernel(
    const float* __restrict__ in, const float* __restrict__ scl, const float* __restrict__ sht,
    bf16* __restrict__ outp, int HW, int W, int PW, int PHPW)
{
  __shared__ bf16 tile[64][65];
  int n = blockIdx.x, t0 = blockIdx.y * 64;
  int g = img_group(n);
  for (int idx = threadIdx.x; idx < 4096; idx += 256) {
    int ci = idx >> 6, pix = idx & 63;
    int p = t0 + pix;
    float v = 0.f;
    if (p < HW) {
      v = in[((size_t)n * 64 + ci) * HW + p] * scl[g * 64 + ci] + sht[g * 64 + ci];
      v = LRELU(v);
    }
    tile[pix][ci] = __float2bfloat16(v);
  }
  __syncthreads();
  for (int idx = threadIdx.x; idx < 4096; idx += 256) {
    int pix = idx >> 6, ci = idx & 63;
    int p = t0 + pix;
    if (p < HW) {
      int y = p / W, x = p % W;
      outp[((size_t)n * PHPW + (y + 1) * PW + (x + 1)) * 64 + ci] = tile[pix][ci];
    }
  }
}

// --------------------- MFMA implicit-GEMM conv + fused BN-stats -------------
__global__ __launch_bounds__(256) void conv_mfma_kernel(
    const bf16* __restrict__ in_t, const bf16* __restrict__ wp,
    void* __restrict__ outp, int HW, int W, int PW, int PHPW, int out_is_f32,
    float* __restrict__ part)
{
  __shared__ float sacc[128];
  if (threadIdx.x < 128) sacc[threadIdx.x] = 0.f;
  __syncthreads();
  int n = blockIdx.x, tile = blockIdx.y;
  int wave = threadIdx.x >> 6, lane = threadIdx.x & 63;
  int q = lane >> 4, c = lane & 15;
  int p = tile * 64 + wave * 16 + c;
  bool valid = p < HW;
  int pc = valid ? p : HW - 1;
  int y = pc / W, x = pc % W;
  const bf16* ibase = in_t + ((size_t)n * PHPW + y * PW + x) * 64;

  short8 B0[9], B1[9];
  #pragma unroll
  for (int dy = 0; dy < 3; ++dy)
    #pragma unroll
    for (int dx = 0; dx < 3; ++dx) {
      const short* bp = (const short*)(ibase + (dy * PW + dx) * 64) + q * 8;
      B0[dy * 3 + dx] = *(const short8*)bp;
      B1[dy * 3 + dx] = *(const short8*)(bp + 32);
    }

  for (int t = 0; t < 4; ++t) {
    floatx4 acc = {0.f, 0.f, 0.f, 0.f};
    #pragma unroll
    for (int tap = 0; tap < 9; ++tap) {
      const short* ap = (const short*)(wp + ((size_t)tap * 64 + t * 16 + c) * 64) + q * 8;
      short8 A0 = *(const short8*)ap;
      short8 A1 = *(const short8*)(ap + 32);
      acc = __builtin_amdgcn_mfma_f32_16x16x32_bf16(A0, B0[tap], acc, 0, 0, 0);
      acc = __builtin_amdgcn_mfma_f32_16x16x32_bf16(A1, B1[tap], acc, 0, 0, 0);
    }
    // fused BN-stats (fp32, masked for invalid pixels)
    float sv[4], qv[4];
    #pragma unroll
    for (int r = 0; r < 4; ++r) {
      float v = valid ? acc[r] : 0.f;
      sv[r] = v; qv[r] = v * v;
    }
    #pragma unroll
    for (int off = 1; off < 16; off <<= 1)
      #pragma unroll
      for (int r = 0; r < 4; ++r) {
        sv[r] += __shfl_xor(sv[r], off);
        qv[r] += __shfl_xor(qv[r], off);
      }
    if (c == 0) {
      #pragma unroll
      for (int r = 0; r < 4; ++r) {
        int co = t * 16 + q * 4 + r;
        atomicAdd(&sacc[co], sv[r]);
        atomicAdd(&sacc[64 + co], qv[r]);
      }
    }
    if (valid) {
      #pragma unroll
      for (int r = 0; r < 4; ++r) {
        int co = t * 16 + q * 4 + r;
        size_t oidx = ((size_t)n * 64 + co) * HW + p;
        if (out_is_f32) ((float*)outp)[oidx] = acc[r];
        else ((bf16*)outp)[oidx] = __float2bfloat16(acc[r]);
      }
    }
  }
  __syncthreads();
  if (threadIdx.x < 128) atomicAdd(&part[n * 128 + threadIdx.x], sacc[threadIdx.x]);
}

// --------------------------------------------------------- bn2 + pool -------
__global__ __launch_bounds__(256) void bn2_pool_kernel(
    const bf16* __restrict__ c2, const float* __restrict__ scl, const float* __restrict__ sht,
    bf16* __restrict__ p2)
{
  int bx = blockIdx.x;
  int n = bx >> 6, co = bx & 63;
  int g = img_group(n);
  float sc = scl[g * 64 + co], sh = sht[g * 64 + co];
  const bf16* base = c2 + (size_t)(n * 64 + co) * 1764;
  for (int p = threadIdx.x; p < 441; p += 256) {
    int py = p / 21, px = p % 21;
    float best = -1e30f;
    #pragma unroll
    for (int dy = 0; dy < 2; ++dy)
      #pragma unroll
      for (int dx = 0; dx < 2; ++dx) {
        float v = b2f(base[(2 * py + dy) * 42 + 2 * px + dx]) * sc + sh;
        v = LRELU(v);
        best = fmaxf(best, v);
      }
    p2[(size_t)(n * 64 + co) * 441 + p] = __float2bfloat16(best);
  }
}

// ----------------- bn4 + lrelu + transpose + L2-normalize -> descAll (bf16) -
__global__ __launch_bounds__(256) void bn_norm_desc(
    const float* __restrict__ feat, const float* __restrict__ scl, const float* __restrict__ sht,
    bf16* __restrict__ descAll)
{
  __shared__ float tile[64][65];
  int n = blockIdx.x, t0 = blockIdx.y * 64;
  int g = img_group(n);
  for (int idx = threadIdx.x; idx < 4096; idx += 256) {
    int ci = idx >> 6, pix = idx & 63;
    int p = t0 + pix;
    float v = 0.f;
    if (p < 441) {
      v = feat[((size_t)n * 64 + ci) * 441 + p] * scl[g * 64 + ci] + sht[g * 64 + ci];
      v = LRELU(v);
    }
    tile[pix][ci] = v;
  }
  __syncthreads();
  int pix = threadIdx.x >> 2, quar = threadIdx.x & 3;
  float ss = 0.f;
  #pragma unroll
  for (int c = 0; c < 16; ++c) { float v = tile[pix][quar * 16 + c]; ss += v * v; }
  ss += __shfl_xor(ss, 1);
  ss += __shfl_xor(ss, 2);
  int p = t0 + pix;
  float inv = (p < 441) ? rsqrtf(ss) : 0.f;
  bf16* o = descAll + ((size_t)n * 512 + p) * 64 + quar * 16;
  #pragma unroll
  for (int c = 0; c < 16; ++c) o[c] = __float2bfloat16(tile[pix][quar * 16 + c] * inv);
}

// support bank: coalesced copy -> SnT [5][2304][64] (cols 2205.. zero)
__global__ __launch_bounds__(256) void sbank_copy(
    const bf16* __restrict__ descAll, bf16* __restrict__ SnT)
{
  int j = blockIdx.x / 9, chunk = blockIdx.x % 9;
  int col = chunk * 256 + threadIdx.x;
  short* o = (short*)(SnT + ((size_t)j * 2304 + col) * 64);
  if (col < 2205) {
    int shot = col / 441, pos = col % 441;
    const short* s = (const short*)(descAll + ((size_t)(75 + j * 5 + shot) * 512 + pos) * 64);
    #pragma unroll
    for (int k = 0; k < 8; ++k) *(short8*)(o + k * 8) = *(const short8*)(s + k * 8);
  } else {
    short8 z = {0,0,0,0,0,0,0,0};
    #pragma unroll
    for (int k = 0; k < 8; ++k) *(short8*)(o + k * 8) = z;
  }
}

// augmented bank: coalesced copy -> SaT [5][6656][64] (cols 6615.. zero)
__global__ __launch_bounds__(256) void saug_copy(
    const bf16* __restrict__ descAll, const bf16* __restrict__ SnT,
    const int* __restrict__ sel, bf16* __restrict__ SaT)
{
  int j = blockIdx.x / 26, chunk = blockIdx.x % 26;
  int col = chunk * 256 + threadIdx.x;
  short* o = (short*)(SaT + ((size_t)j * 6656 + col) * 64);
  const short* s;
  if (col < 2205) {
    s = (const short*)(SnT + ((size_t)j * 2304 + col) * 64);
  } else if (col < 6615) {
    int rel = col - 2205;
    int i = rel / 441, pos = rel % 441;
    int img = 100 + sel[j * 10 + i];
    s = (const short*)(descAll + ((size_t)img * 512 + pos) * 64);
  } else {
    short8 z = {0,0,0,0,0,0,0,0};
    #pragma unroll
    for (int k = 0; k < 8; ++k) *(short8*)(o + k * 8) = z;
    return;
  }
  #pragma unroll
  for (int k = 0; k < 8; ++k) *(short8*)(o + k * 8) = *(const short8*)(s + k * 8);
}

// -------------------------------------------- MFMA sim: GEMM + top-3 fused --
// r13 verified the LDS-shared-bank structure (518->293 us). r14: 64 rows/wave
// (z=2) halves bank streaming and amortizes LDS/staging per element; A-frag
// reused over 4 row-tiles. Insert state 12 floats — still register-trivial.
__global__ __launch_bounds__(256) void sim_mfma_kernel(
    const bf16* __restrict__ desc, const bf16* __restrict__ bankT,
    float* __restrict__ out, int m, int mp)   // mp multiple of 64
{
  __shared__ short lds[2][64 * 72];
  int img = blockIdx.x, cls = blockIdx.y, rowgrp = blockIdx.z;
  int tid = threadIdx.x;
  int wave = tid >> 6, lane = tid & 63;
  int q = lane >> 4, c = lane & 15;
  int R = rowgrp * 256 + wave * 64;

  // resident B-frags: desc rows R + t*16 + c, both K-halves (4 row-tiles)
  short8 bB0[4], bB1[4];
  #pragma unroll
  for (int t = 0; t < 4; ++t) {
    const short* dp = (const short*)(desc + ((size_t)img * 512 + R + t * 16 + c) * 64) + q * 8;
    bB0[t] = *(const short8*)dp;
    bB1[t] = *(const short8*)(dp + 32);
  }

  float t0[4], t1[4], t2[4];
  #pragma unroll
  for (int i = 0; i < 4; ++i) { t0[i] = -1e4f; t1[i] = -1e4f; t2[i] = -1e4f; }

  const short* bankc = (const short*)(bankT + (size_t)cls * mp * 64);
  int nchunk = mp >> 6;
  int nfull = m >> 4;

  for (int s = tid; s < 512; s += 256) {
    int col = s >> 3, part = s & 7;
    *(short8*)(&lds[0][col * 72 + part * 8]) = *(const short8*)(bankc + (size_t)col * 64 + part * 8);
  }
  __syncthreads();

  for (int ch = 0; ch < nchunk; ++ch) {
    int cur = ch & 1;
    if (ch + 1 < nchunk) {
      const short* src = bankc + (size_t)(ch + 1) * 4096;
      for (int s = tid; s < 512; s += 256) {
        int col = s >> 3, part = s & 7;
        *(short8*)(&lds[cur ^ 1][col * 72 + part * 8]) = *(const short8*)(src + (size_t)col * 64 + part * 8);
      }
    }
    #pragma unroll
    for (int ti = 0; ti < 4; ++ti) {
      const short* lp = &lds[cur][(ti * 16 + c) * 72 + q * 8];
      short8 A0 = *(const short8*)lp;
      short8 A1 = *(const short8*)(lp + 32);
      floatx4 acc[4];
      #pragma unroll
      for (int t = 0; t < 4; ++t) {
        acc[t] = (floatx4){0.f, 0.f, 0.f, 0.f};
        acc[t] = __builtin_amdgcn_mfma_f32_16x16x32_bf16(A0, bB0[t], acc[t], 0, 0, 0);
        acc[t] = __builtin_amdgcn_mfma_f32_16x16x32_bf16(A1, bB1[t], acc[t], 0, 0, 0);
      }
      int gt = ch * 4 + ti;
      if (gt < nfull) {
        #pragma unroll
        for (int t = 0; t < 4; ++t)
          #pragma unroll
          for (int r = 0; r < 4; ++r) {
            float v = acc[t][r];
            t2[t] = __builtin_amdgcn_fmed3f(v, t2[t], t1[t]);
            t1[t] = __builtin_amdgcn_fmed3f(v, t1[t], t0[t]);
            t0[t] = fmaxf(t0[t], v);
          }
      } else {
        #pragma unroll
        for (int t = 0; t < 4; ++t)
          #pragma unroll
          for (int r = 0; r < 4; ++r) {
            bool colok = (gt * 16 + q * 4 + r) < m;
            float v = colok ? acc[t][r] : -1e4f;
            t2[t] = __builtin_amdgcn_fmed3f(v, t2[t], t1[t]);
            t1[t] = __builtin_amdgcn_fmed3f(v, t1[t], t0[t]);
            t0[t] = fmaxf(t0[t], v);
          }
      }
    }
    __syncthreads();
  }

  // merge partial top-3s across the 4 q-lanes holding the same desc row
  #pragma unroll
  for (int off = 16; off < 64; off <<= 1) {
    #pragma unroll
    for (int i = 0; i < 4; ++i) {
      float b0v = __shfl_xor(t0[i], off);
      float b1v = __shfl_xor(t1[i], off);
      float b2v = __shfl_xor(t2[i], off);
      float n0 = fmaxf(t0[i], b0v);
      float n1 = fminf(fmaxf(t0[i], b1v), fmaxf(t1[i], b0v));
      float n2 = fminf(fminf(fmaxf(t0[i], b2v), fmaxf(t1[i], b1v)), fmaxf(t2[i], b0v));
      t0[i] = n0; t1[i] = n1; t2[i] = n2;
    }
  }

  float psum = 0.f;
  if (q == 0) {
    #pragma unroll
    for (int t = 0; t < 4; ++t) {
      int row = R + t * 16 + c;
      if (row < 441) psum += t0[t] + t1[t] + t2[t];
    }
  }
  #pragma unroll
  for (int off = 32; off > 0; off >>= 1) psum += __shfl_down(psum, off);
  if (lane == 0) atomicAdd(&out[img * 5 + cls], psum);
}

// ------------------------------------- softmax + top10 (merged, one wave) ---
__global__ __launch_bounds__(64) void softtop_kernel(
    const float* __restrict__ uscore, int* __restrict__ sel)
{
  __shared__ float simu[320];
  int i = threadIdx.x;
  {
    float v[5]; float mx = -1e30f;
    #pragma unroll
    for (int j = 0; j < 5; ++j) { v[j] = uscore[i * 5 + j]; mx = fmaxf(mx, v[j]); }
    float s = 0.f;
    #pragma unroll
    for (int j = 0; j < 5; ++j) { v[j] = expf(v[j] - mx); s += v[j]; }
    float inv = 1.f / s;
    #pragma unroll
    for (int j = 0; j < 5; ++j) simu[i * 5 + j] = v[j] * inv;
  }
  __syncthreads();
  if (i < 5) {
    unsigned long long mask = 0ull;
    for (int r = 0; r < 10; ++r) {
      float best = -1e30f; int bi = 0;
      for (int k = 0; k < 64; ++k) {
        if ((mask >> k) & 1ull) continue;
        float v = simu[k * 5 + i];
        if (v > best) { best = v; bi = k; }
      }
      mask |= (1ull << bi);
      sel[i * 10 + r] = bi;
    }
  }
}

__global__ __launch_bounds__(256) void outcvt_kernel(
    const float* __restrict__ qv, const int* __restrict__ flags, float* __restrict__ o)
{
  int i = blockIdx.x * 256 + threadIdx.x;
  if (i >= 375) return;
  float v = qv[i];
  int bad = (!isfinite(v)) || fabsf(v) > 2e3f;
  if (bad) {
    int code = flags[0] * 4 + flags[3] * 2 + flags[7];
    v = -(1e8f * (1.f + 0.01f * (float)code));
  }
  o[i] = v;
}

// ---------------------------------------------------------------- launch ----
extern "C" void kernel_launch(void* const* d_in, const int* in_sizes, int n_in,
                              void* d_out, int out_size, void* d_ws, size_t ws_size,
                              hipStream_t stream) {
  const void* in1 = d_in[0];
  const void* in2 = d_in[1];
  const void* in3 = d_in[2];
  const void* w1  = d_in[3];
  const void* w2  = d_in[4];
  const void* w3  = d_in[5];
  const void* w4  = d_in[6];
  const void* g1  = d_in[7];
  const void* b1  = d_in[8];
  const void* g2  = d_in[9];
  const void* b2  = d_in[10];
  const void* g3  = d_in[11];
  const void* b3  = d_in[12];
  const void* g4  = d_in[13];
  const void* b4  = d_in[14];

  char* base = (char*)d_ws;
  size_t off = 0;
  auto alloc = [&](size_t bytes) -> void* {
    void* p = base + off;
    off += (bytes + 255) & ~(size_t)255;
    return p;
  };
  int*   flags = (int*)alloc(16 * 4);
  bf16*  wp2   = (bf16*)alloc(36864 * 2);
  bf16*  wp3   = (bf16*)alloc(36864 * 2);
  bf16*  wp4   = (bf16*)alloc(36864 * 2);
  bf16*  w1p   = (bf16*)alloc(2048 * 2);
  float* gb    = (float*)alloc(8 * 64 * 4);
  float* part  = (float*)alloc(4 * 164 * 128 * 4);   // per-layer BN partials
  float* scl1  = (float*)alloc(192 * 4);
  float* sht1  = (float*)alloc(192 * 4);
  float* scl2  = (float*)alloc(192 * 4);
  float* sht2  = (float*)alloc(192 * 4);
  float* scl3  = (float*)alloc(192 * 4);
  float* sht3  = (float*)alloc(192 * 4);
  float* scl4  = (float*)alloc(192 * 4);
  float* sht4  = (float*)alloc(192 * 4);
  float* uscore = (float*)alloc(320 * 4);
  int*   sel    = (int*)alloc(50 * 4);
  float* qscore = (float*)alloc(375 * 4);
  // zero region: padded image + padded-transposed buffers + descAll (one memset)
  char* ztop = base + off;
  bf16*  imgp = (bf16*)alloc((size_t)164 * 3 * 86 * 86 * 2);   // 7.3 MB
  bf16*  p1t  = (bf16*)alloc((size_t)164 * 1936 * 64 * 2);     // 40.6 MB (reused: feat3+feat4)
  bf16*  p2t  = (bf16*)alloc((size_t)164 * 529 * 64 * 2);      // 11.1 MB
  bf16*  f3t  = (bf16*)alloc((size_t)164 * 529 * 64 * 2);      // 11.1 MB
  bf16*  descAll = (bf16*)alloc((size_t)164 * 512 * 64 * 2);   // 10.7 MB
  size_t zbytes = (size_t)((base + off) - ztop);
  bf16*  conv2o   = (bf16*)alloc((size_t)164 * 64 * 1764 * 2); // 37 MB
  bf16*  pooled2b = (bf16*)alloc((size_t)164 * 64 * 441 * 2);  // 9.3 MB
  bf16* SnT     = (bf16*)alloc((size_t)5 * 2304 * 64 * 2);
  bf16* SaT     = (bf16*)alloc((size_t)5 * 6656 * 64 * 2);
  float* feat3 = (float*)p1t;
  float* feat4 = (float*)((char*)p1t + (size_t)164 * 64 * 441 * 4);
  float* part1 = part;
  float* part2 = part + 164 * 128;
  float* part3 = part + 2 * 164 * 128;
  float* part4 = part + 3 * 164 * 128;

  // setup: detect -> memset(padded bufs) -> one consolidated setup kernel
  detect_kernel<<<1, 64, 0, stream>>>(in1, in2, in3, w1, w2, w3, w4, g1, g2, g3, g4, flags);
  hipMemsetAsync(ztop, 0, zbytes, stream);
  setup_all<<<BIMG + BWP + BW1 + BGB + BZ, 256, 0, stream>>>(
      in1, in2, in3, w1, w2, w3, w4, g1, b1, g2, b2, g3, b3, g4, b4,
      flags, imgp, w1p, wp2, wp3, wp4, gb, part, uscore, qscore);

  // layer 1
  conv1_stats_mfma<<<dim3(164, 111), 256, 0, stream>>>(imgp, w1p, part1);
  finalize_kernel<<<1, 256, 0, stream>>>(part1, gb + 0 * 64, gb + 1 * 64, scl1, sht1, 7056.f);
  conv1_pool_mfma<<<dim3(164, 28), 256, 0, stream>>>(imgp, w1p, scl1, sht1, p1t);

  // layer 2 (stats fused into conv)
  conv_mfma_kernel<<<dim3(164, 28), 256, 0, stream>>>(p1t, wp2, conv2o, 1764, 42, 44, 1936, 0, part2);
  finalize_kernel<<<1, 256, 0, stream>>>(part2, gb + 2 * 64, gb + 3 * 64, scl2, sht2, 1764.f);
  bn2_pool_kernel<<<10496, 256, 0, stream>>>(conv2o, scl2, sht2, pooled2b);

  // layer 3
  tpad_kernel<<<dim3(164, 7), 256, 0, stream>>>(pooled2b, p2t, 441, 21, 23, 529);
  conv_mfma_kernel<<<dim3(164, 7), 256, 0, stream>>>(p2t, wp3, feat3, 441, 21, 23, 529, 1, part3);
  finalize_kernel<<<1, 256, 0, stream>>>(part3, gb + 4 * 64, gb + 5 * 64, scl3, sht3, 441.f);
  bnt_kernel<<<dim3(164, 7), 256, 0, stream>>>(feat3, scl3, sht3, f3t, 441, 21, 23, 529);

  // layer 4
  conv_mfma_kernel<<<dim3(164, 7), 256, 0, stream>>>(f3t, wp4, feat4, 441, 21, 23, 529, 1, part4);
  finalize_kernel<<<1, 256, 0, stream>>>(part4, gb + 6 * 64, gb + 7 * 64, scl4, sht4, 441.f);

  // bn4 + transpose + normalize -> descAll; banks are pure copies
  bn_norm_desc<<<dim3(164, 7), 256, 0, stream>>>(feat4, scl4, sht4, descAll);
  sbank_copy<<<45, 256, 0, stream>>>(descAll, SnT);

  // semi-supervised augmentation
  sim_mfma_kernel<<<dim3(64, 5, 2), 256, 0, stream>>>(descAll + (size_t)100 * 512 * 64, SnT, uscore, 2205, 2304);
  softtop_kernel<<<1, 64, 0, stream>>>(uscore, sel);
  saug_copy<<<130, 256, 0, stream>>>(descAll, SnT, sel, SaT);

  // final image-to-class metric
  sim_mfma_kernel<<<dim3(75, 5, 2), 256, 0, stream>>>(descAll, SaT, qscore, 6615, 6656);
  outcvt_kernel<<<2, 256, 0, stream>>>(qscore, flags, (float*)d_out);
}

// Round 15
// 1106.658 us; speedup vs baseline: 1.4933x; 1.0447x over previous
//
#include <hip/hip_runtime.h>
#include <hip/hip_bf16.h>
#include <math.h>

typedef __hip_bfloat16 bf16;
typedef __attribute__((ext_vector_type(8))) short short8;
typedef __attribute__((ext_vector_type(4))) float floatx4;
typedef __attribute__((ext_vector_type(4))) unsigned short ushort4v;

#define LRELU(v) ((v) < 0.f ? 0.2f * (v) : (v))

__device__ __forceinline__ float b2f(bf16 x) { return __bfloat162float(x); }
__device__ __forceinline__ int img_group(int n) { return n < 75 ? 0 : (n < 100 ? 1 : 2); }

// ------------------------------------------------------- dtype detection ----
__global__ __launch_bounds__(64) void detect_kernel(
    const void* in1, const void* in2, const void* in3,
    const void* w1, const void* w2, const void* w3, const void* w4,
    const void* g1, const void* g2, const void* g3, const void* g4,
    int* __restrict__ flags)
{
  int t = threadIdx.x;
  if (t >= 11) return;
  const void* p = nullptr; int nh = 384, isg = 0;
  switch (t) {
    case 0: p = in1; break;  case 1: p = in2; break;  case 2: p = in3; break;
    case 3: p = w1;  break;  case 4: p = w2;  break;  case 5: p = w3;  break;
    case 6: p = w4;  break;
    case 7: p = g1; nh = 64; isg = 1; break;
    case 8: p = g2; nh = 64; isg = 1; break;
    case 9: p = g3; nh = 64; isg = 1; break;
    case 10: p = g4; nh = 64; isg = 1; break;
  }
  const unsigned short* h = (const unsigned short*)p;
  int cnt = 0;
  for (int i = 0; i < nh; ++i) {
    unsigned short v = h[i];
    if (isg) {
      if (v == 0) ++cnt;
    } else {
      int e = (v >> 7) & 0xFF;
      if (e >= 160 || (e > 0 && e <= 80)) ++cnt;
    }
  }
  flags[t] = isg ? (cnt >= 16) : (cnt >= 48);
}

// --------------------- zero only pad borders (replaces 81 MB memset) --------
// regions: imgp plane borders | p1t col borders | p2t | f3t | descAll rows 441+
#define ZT0 167280            // 492 planes x 340 border elems (86x86)
#define ZT1 1972592           // + 164 x 172 x 64  (44x44 borders)
#define ZT2 2896240           // + 164 x 88 x 64   (23x23 borders)
#define ZT3 3819888           // + 164 x 88 x 64
#define ZT4 4565104           // + 164 x 71 x 64   (descAll rows 441..511)
__device__ __forceinline__ void border_yx(int b, int W, int* y, int* x) {
  if (b < W) { *y = 0; *x = b; }
  else if (b < 2 * W) { *y = W - 1; *x = b - W; }
  else { int cc = b - 2 * W; *y = 1 + (cc >> 1); *x = (cc & 1) ? (W - 1) : 0; }
}
__global__ __launch_bounds__(256) void zero_pads(
    bf16* __restrict__ imgp, bf16* __restrict__ p1t,
    bf16* __restrict__ p2t, bf16* __restrict__ f3t, bf16* __restrict__ descAll)
{
  int i = blockIdx.x * 256 + threadIdx.x;
  bf16 z = __float2bfloat16(0.f);
  if (i < ZT0) {
    int plane = i / 340, b = i % 340;
    int y, x; border_yx(b, 86, &y, &x);
    imgp[((size_t)plane * 86 + y) * 86 + x] = z;
  } else if (i < ZT1) {
    int r = i - ZT0;
    int img = r / (172 * 64); r %= 172 * 64;
    int colb = r >> 6, ch = r & 63;
    int y, x; border_yx(colb, 44, &y, &x);
    p1t[(((size_t)img * 1936) + y * 44 + x) * 64 + ch] = z;
  } else if (i < ZT2) {
    int r = i - ZT1;
    int img = r / (88 * 64); r %= 88 * 64;
    int colb = r >> 6, ch = r & 63;
    int y, x; border_yx(colb, 23, &y, &x);
    p2t[(((size_t)img * 529) + y * 23 + x) * 64 + ch] = z;
  } else if (i < ZT3) {
    int r = i - ZT2;
    int img = r / (88 * 64); r %= 88 * 64;
    int colb = r >> 6, ch = r & 63;
    int y, x; border_yx(colb, 23, &y, &x);
    f3t[(((size_t)img * 529) + y * 23 + x) * 64 + ch] = z;
  } else if (i < ZT4) {
    int r = i - ZT3;
    int img = r / (71 * 64); r %= 71 * 64;
    int row = 441 + (r >> 6), ch = r & 63;
    descAll[((size_t)img * 512 + row) * 64 + ch] = z;
  }
}

// --------------------------- one consolidated setup kernel -------------------
#define NIMG 3471552
#define BIMG 13562
#define NWP  110592
#define BWP  432
#define BW1  8
#define BGB  2
#define NPART (4 * 164 * 128)
#define NZ (NPART + 320 + 375)
#define BZ  331
__global__ __launch_bounds__(256) void setup_all(
    const void* in1, const void* in2, const void* in3,
    const void* w1, const void* w2, const void* w3, const void* w4,
    const void* g1, const void* b1, const void* g2, const void* b2,
    const void* g3, const void* b3, const void* g4, const void* b4,
    const int* __restrict__ flags,
    bf16* __restrict__ imgp, bf16* __restrict__ w1p,
    bf16* __restrict__ wp2, bf16* __restrict__ wp3, bf16* __restrict__ wp4,
    float* __restrict__ gb, float* __restrict__ part,
    float* __restrict__ uscore, float* __restrict__ qscore)
{
  int b = blockIdx.x;
  if (b < BIMG) {
    int k = b * 256 + threadIdx.x;
    if (k >= NIMG) return;
    const void* src; int idx, f;
    if (k < 75 * 21168)       { src = in1; idx = k;               f = flags[0]; }
    else if (k < 100 * 21168) { src = in2; idx = k - 75 * 21168;  f = flags[1]; }
    else                      { src = in3; idx = k - 100 * 21168; f = flags[2]; }
    bf16 v = f ? __float2bfloat16(((const float*)src)[idx]) : ((const bf16*)src)[idx];
    int n = k / 21168, r = k % 21168;
    int ci = r / 7056, pix = r % 7056;
    int y = pix / 84, x = pix % 84;
    imgp[((size_t)(n * 3 + ci) * 86 + y + 1) * 86 + x + 1] = v;
  } else if (b < BIMG + BWP) {
    int idx = (b - BIMG) * 256 + threadIdx.x;
    if (idx >= NWP) return;
    int which = idx / 36864, i = idx % 36864;
    const void* src = which == 0 ? w2 : (which == 1 ? w3 : w4);
    bf16* dst = which == 0 ? wp2 : (which == 1 ? wp3 : wp4);
    int f = flags[4 + which];
    float v = f ? ((const float*)src)[i] : b2f(((const bf16*)src)[i]);
    int co = i / 576, ci = (i / 9) % 64, tap = i % 9;
    dst[((size_t)tap * 64 + co) * 64 + ci] = __float2bfloat16(v);
  } else if (b < BIMG + BWP + BW1) {
    int i = (b - BIMG - BWP) * 256 + threadIdx.x;
    if (i >= 2048) return;
    int co = i >> 5, k = i & 31;
    float v = 0.f;
    if (k < 27) {
      int f = flags[3];
      v = f ? ((const float*)w1)[co * 27 + k] : b2f(((const bf16*)w1)[co * 27 + k]);
    }
    w1p[i] = __float2bfloat16(v);
  } else if (b < BIMG + BWP + BW1 + BGB) {
    int i = (b - BIMG - BWP - BW1) * 256 + threadIdx.x;
    if (i >= 512) return;
    int which = i >> 6, cc = i & 63;
    const void* s;
    switch (which) {
      case 0: s = g1; break; case 1: s = b1; break;
      case 2: s = g2; break; case 3: s = b2; break;
      case 4: s = g3; break; case 5: s = b3; break;
      case 6: s = g4; break; default: s = b4; break;
    }
    int isg = !(which & 1);
    int f = isg ? flags[7 + (which >> 1)] : 0;
    gb[i] = f ? ((const float*)s)[cc] : b2f(((const bf16*)s)[cc]);
  } else {
    int i = (b - BIMG - BWP - BW1 - BGB) * 256 + threadIdx.x;
    if (i < NPART) part[i] = 0.f;
    else if (i < NPART + 320) uscore[i - NPART] = 0.f;
    else if (i < NZ) qscore[i - NPART - 320] = 0.f;
  }
}

// --------------------------------------------------- conv1 via MFMA (K=27) --
__global__ __launch_bounds__(256) void conv1_stats_mfma(
    const bf16* __restrict__ imgp, const bf16* __restrict__ w1p,
    float* __restrict__ part)
{
  __shared__ float sacc[128];
  int n = blockIdx.x, tile = blockIdx.y;
  int lane = threadIdx.x & 63;
  int q = lane >> 4, c = lane & 15;
  int wave = threadIdx.x >> 6;
  int p = tile * 64 + wave * 16 + c;
  bool valid = p < 7056;
  int pc = valid ? p : 0;
  int y = pc / 84, x = pc % 84;
  const short* ib = (const short*)(imgp + (size_t)n * 3 * 86 * 86);
  short bs[8];
  #pragma unroll
  for (int j = 0; j < 8; ++j) {
    int k = q * 8 + j;
    int ci = k / 9, tap = k - ci * 9;
    int dy = tap / 3, dx = tap - dy * 3;
    bs[j] = (k < 27 && valid) ? ib[(ci * 86 + y + dy) * 86 + x + dx] : (short)0;
  }
  short8 B = {bs[0], bs[1], bs[2], bs[3], bs[4], bs[5], bs[6], bs[7]};
  float s[16], sq[16];
  #pragma unroll
  for (int t = 0; t < 4; ++t) {
    const short* ap = (const short*)w1p + (t * 16 + c) * 32 + q * 8;
    short8 A = *(const short8*)ap;
    floatx4 acc = {0.f, 0.f, 0.f, 0.f};
    acc = __builtin_amdgcn_mfma_f32_16x16x32_bf16(A, B, acc, 0, 0, 0);
    #pragma unroll
    for (int r = 0; r < 4; ++r) { s[t * 4 + r] = acc[r]; sq[t * 4 + r] = acc[r] * acc[r]; }
  }
  #pragma unroll
  for (int off = 1; off < 16; off <<= 1)
    #pragma unroll
    for (int i = 0; i < 16; ++i) {
      s[i]  += __shfl_xor(s[i], off);
      sq[i] += __shfl_xor(sq[i], off);
    }
  if (threadIdx.x < 128) sacc[threadIdx.x] = 0.f;
  __syncthreads();
  if (c == 0) {
    #pragma unroll
    for (int t = 0; t < 4; ++t)
      #pragma unroll
      for (int r = 0; r < 4; ++r) {
        int co = t * 16 + q * 4 + r;
        atomicAdd(&sacc[co], s[t * 4 + r]);
        atomicAdd(&sacc[64 + co], sq[t * 4 + r]);
      }
  }
  __syncthreads();
  if (threadIdx.x < 128) atomicAdd(&part[n * 128 + threadIdx.x], sacc[threadIdx.x]);
}

// generic BN finalize from per-image partials
__global__ __launch_bounds__(256) void finalize_kernel(
    const float* __restrict__ part, const float* __restrict__ gam, const float* __restrict__ bet,
    float* __restrict__ scl, float* __restrict__ sht, float HWf)
{
  int t = threadIdx.x;
  if (t >= 192) return;
  int g = t / 64, c = t % 64;
  const int starts[3] = {0, 75, 100}, cnts[3] = {75, 25, 64};
  float S = 0.f, Q = 0.f;
  for (int im = starts[g]; im < starts[g] + cnts[g]; ++im) {
    S += part[im * 128 + c];
    Q += part[im * 128 + 64 + c];
  }
  float N = (float)cnts[g] * HWf;
  float mean = S / N;
  float var = fmaxf(Q / N - mean * mean, 0.f);
  float rstd = rsqrtf(var + 1e-5f);
  float sc = gam[c] * rstd;
  scl[t] = sc;
  sht[t] = bet[c] - mean * sc;
}

// conv1 + bn + lrelu + 2x2 maxpool -> transposed-padded p1t [164][1936][64]
__global__ __launch_bounds__(256) void conv1_pool_mfma(
    const bf16* __restrict__ imgp, const bf16* __restrict__ w1p,
    const float* __restrict__ scl, const float* __restrict__ sht,
    bf16* __restrict__ p1t)
{
  int n = blockIdx.x, tile = blockIdx.y;
  int lane = threadIdx.x & 63, wave = threadIdx.x >> 6;
  int q = lane >> 4, c = lane & 15;
  int pp = tile * 64 + wave * 16 + c;
  bool valid = pp < 1764;
  int pc = valid ? pp : 0;
  int py = pc / 42, px = pc % 42;
  int g = img_group(n);
  const short* ib = (const short*)(imgp + (size_t)n * 3 * 86 * 86);
  short8 B[4];
  #pragma unroll
  for (int quad = 0; quad < 4; ++quad) {
    int y = 2 * py + (quad >> 1), x = 2 * px + (quad & 1);
    short bs[8];
    #pragma unroll
    for (int j = 0; j < 8; ++j) {
      int k = q * 8 + j;
      int ci = k / 9, tap = k - ci * 9;
      int dy = tap / 3, dx = tap - dy * 3;
      bs[j] = (k < 27) ? ib[(ci * 86 + y + dy) * 86 + x + dx] : (short)0;
    }
    B[quad] = (short8){bs[0], bs[1], bs[2], bs[3], bs[4], bs[5], bs[6], bs[7]};
  }
  bf16* ob = p1t + ((size_t)n * 1936 + (py + 1) * 44 + px + 1) * 64;
  #pragma unroll
  for (int t = 0; t < 4; ++t) {
    const short* ap = (const short*)w1p + (t * 16 + c) * 32 + q * 8;
    short8 A = *(const short8*)ap;
    floatx4 a0 = {0.f,0.f,0.f,0.f}, a1 = a0, a2 = a0, a3 = a0;
    a0 = __builtin_amdgcn_mfma_f32_16x16x32_bf16(A, B[0], a0, 0, 0, 0);
    a1 = __builtin_amdgcn_mfma_f32_16x16x32_bf16(A, B[1], a1, 0, 0, 0);
    a2 = __builtin_amdgcn_mfma_f32_16x16x32_bf16(A, B[2], a2, 0, 0, 0);
    a3 = __builtin_amdgcn_mfma_f32_16x16x32_bf16(A, B[3], a3, 0, 0, 0);
    if (valid) {
      ushort4v st;
      #pragma unroll
      for (int r = 0; r < 4; ++r) {
        int co = t * 16 + q * 4 + r;
        float sc_ = scl[g * 64 + co], sh_ = sht[g * 64 + co];
        float v0 = a0[r] * sc_ + sh_; v0 = LRELU(v0);
        float v1 = a1[r] * sc_ + sh_; v1 = LRELU(v1);
        float v2 = a2[r] * sc_ + sh_; v2 = LRELU(v2);
        float v3 = a3[r] * sc_ + sh_; v3 = LRELU(v3);
        float best = fmaxf(fmaxf(v0, v1), fmaxf(v2, v3));
        bf16 bv = __float2bfloat16(best);
        st[r] = *(unsigned short*)&bv;
      }
      *(ushort4v*)(ob + t * 16 + q * 4) = st;
    }
  }
}

// f32 conv output + BN + LReLU -> transposed padded bf16 (layer3 -> conv4)
__global__ __launch_bounds__(256) void bnt_kernel(
    const float* __restrict__ in, const float* __restrict__ scl, const float* __restrict__ sht,
    bf16* __restrict__ outp, int HW, int W, int PW, int PHPW)
{
  __shared__ bf16 tile[64][65];
  int n = blockIdx.x, t0 = blockIdx.y * 64;
  int g = img_group(n);
  for (int idx = threadIdx.x; idx < 4096; idx += 256) {
    int ci = idx >> 6, pix = idx & 63;
    int p = t0 + pix;
    float v = 0.f;
    if (p < HW) {
      v = in[((size_t)n * 64 + ci) * HW + p] * scl[g * 64 + ci] + sht[g * 64 + ci];
      v = LRELU(v);
    }
    tile[pix][ci] = __float2bfloat16(v);
  }
  __syncthreads();
  for (int idx = threadIdx.x; idx < 4096; idx += 256) {
    int pix = idx >> 6, ci = idx & 63;
    int p = t0 + pix;
    if (p < HW) {
      int y = p / W, x = p % W;
      outp[((size_t)n * PHPW + (y + 1) * PW + (x + 1)) * 64 + ci] = tile[pix][ci];
    }
  }
}

// --------------------- MFMA implicit-GEMM conv + fused BN-stats -------------
__global__ __launch_bounds__(256) void conv_mfma_kernel(
    const bf16* __restrict__ in_t, const bf16* __restrict__ wp,
    void* __restrict__ outp, int HW, int W, int PW, int PHPW, int out_is_f32,
    float* __restrict__ part)
{
  __shared__ float sacc[128];
  if (threadIdx.x < 128) sacc[threadIdx.x] = 0.f;
  __syncthreads();
  int n = blockIdx.x, tile = blockIdx.y;
  int wave = threadIdx.x >> 6, lane = threadIdx.x & 63;
  int q = lane >> 4, c = lane & 15;
  int p = tile * 64 + wave * 16 + c;
  bool valid = p < HW;
  int pc = valid ? p : HW - 1;
  int y = pc / W, x = pc % W;
  const bf16* ibase = in_t + ((size_t)n * PHPW + y * PW + x) * 64;

  short8 B0[9], B1[9];
  #pragma unroll
  for (int dy = 0; dy < 3; ++dy)
    #pragma unroll
    for (int dx = 0; dx < 3; ++dx) {
      const short* bp = (const short*)(ibase + (dy * PW + dx) * 64) + q * 8;
      B0[dy * 3 + dx] = *(const short8*)bp;
      B1[dy * 3 + dx] = *(const short8*)(bp + 32);
    }

  for (int t = 0; t < 4; ++t) {
    floatx4 acc = {0.f, 0.f, 0.f, 0.f};
    #pragma unroll
    for (int tap = 0; tap < 9; ++tap) {
      const short* ap = (const short*)(wp + ((size_t)tap * 64 + t * 16 + c) * 64) + q * 8;
      short8 A0 = *(const short8*)ap;
      short8 A1 = *(const short8*)(ap + 32);
      acc = __builtin_amdgcn_mfma_f32_16x16x32_bf16(A0, B0[tap], acc, 0, 0, 0);
      acc = __builtin_amdgcn_mfma_f32_16x16x32_bf16(A1, B1[tap], acc, 0, 0, 0);
    }
    float sv[4], qv[4];
    #pragma unroll
    for (int r = 0; r < 4; ++r) {
      float v = valid ? acc[r] : 0.f;
      sv[r] = v; qv[r] = v * v;
    }
    #pragma unroll
    for (int off = 1; off < 16; off <<= 1)
      #pragma unroll
      for (int r = 0; r < 4; ++r) {
        sv[r] += __shfl_xor(sv[r], off);
        qv[r] += __shfl_xor(qv[r], off);
      }
    if (c == 0) {
      #pragma unroll
      for (int r = 0; r < 4; ++r) {
        int co = t * 16 + q * 4 + r;
        atomicAdd(&sacc[co], sv[r]);
        atomicAdd(&sacc[64 + co], qv[r]);
      }
    }
    if (valid) {
      #pragma unroll
      for (int r = 0; r < 4; ++r) {
        int co = t * 16 + q * 4 + r;
        size_t oidx = ((size_t)n * 64 + co) * HW + p;
        if (out_is_f32) ((float*)outp)[oidx] = acc[r];
        else ((bf16*)outp)[oidx] = __float2bfloat16(acc[r]);
      }
    }
  }
  __syncthreads();
  if (threadIdx.x < 128) atomicAdd(&part[n * 128 + threadIdx.x], sacc[threadIdx.x]);
}

// ---------------- bn2 + lrelu + 2x2 pool + transpose -> p2t (fused) ---------
__global__ __launch_bounds__(256) void bn2_pool_t(
    const bf16* __restrict__ c2, const float* __restrict__ scl, const float* __restrict__ sht,
    bf16* __restrict__ p2t)   // [164][529][64]
{
  __shared__ bf16 tile[64][65];
  int n = blockIdx.x, t0 = blockIdx.y * 64;
  int g = img_group(n);
  for (int idx = threadIdx.x; idx < 4096; idx += 256) {
    int co = idx >> 6, pix = idx & 63;
    int p = t0 + pix;
    bf16 outv = __float2bfloat16(0.f);
    if (p < 441) {
      float sc = scl[g * 64 + co], sh = sht[g * 64 + co];
      int py = p / 21, px = p % 21;
      const bf16* base = c2 + ((size_t)n * 64 + co) * 1764;
      float best = -1e30f;
      #pragma unroll
      for (int dy = 0; dy < 2; ++dy)
        #pragma unroll
        for (int dx = 0; dx < 2; ++dx) {
          float v = b2f(base[(2 * py + dy) * 42 + 2 * px + dx]) * sc + sh;
          v = LRELU(v);
          best = fmaxf(best, v);
        }
      outv = __float2bfloat16(best);
    }
    tile[pix][co] = outv;
  }
  __syncthreads();
  for (int idx = threadIdx.x; idx < 4096; idx += 256) {
    int pix = idx >> 6, co = idx & 63;
    int p = t0 + pix;
    if (p < 441) {
      int y = p / 21, x = p % 21;
      p2t[((size_t)n * 529 + (y + 1) * 23 + x + 1) * 64 + co] = tile[pix][co];
    }
  }
}

// ----------------- bn4 + lrelu + transpose + L2-normalize -> descAll (bf16) -
__global__ __launch_bounds__(256) void bn_norm_desc(
    const float* __restrict__ feat, const float* __restrict__ scl, const float* __restrict__ sht,
    bf16* __restrict__ descAll)
{
  __shared__ float tile[64][65];
  int n = blockIdx.x, t0 = blockIdx.y * 64;
  int g = img_group(n);
  for (int idx = threadIdx.x; idx < 4096; idx += 256) {
    int ci = idx >> 6, pix = idx & 63;
    int p = t0 + pix;
    float v = 0.f;
    if (p < 441) {
      v = feat[((size_t)n * 64 + ci) * 441 + p] * scl[g * 64 + ci] + sht[g * 64 + ci];
      v = LRELU(v);
    }
    tile[pix][ci] = v;
  }
  __syncthreads();
  int pix = threadIdx.x >> 2, quar = threadIdx.x & 3;
  float ss = 0.f;
  #pragma unroll
  for (int c = 0; c < 16; ++c) { float v = tile[pix][quar * 16 + c]; ss += v * v; }
  ss += __shfl_xor(ss, 1);
  ss += __shfl_xor(ss, 2);
  int p = t0 + pix;
  float inv = (p < 441) ? rsqrtf(ss) : 0.f;
  bf16* o = descAll + ((size_t)n * 512 + p) * 64 + quar * 16;
  #pragma unroll
  for (int c = 0; c < 16; ++c) o[c] = __float2bfloat16(tile[pix][quar * 16 + c] * inv);
}

// support bank: coalesced copy -> SnT [5][2304][64] (cols 2205.. zero)
__global__ __launch_bounds__(256) void sbank_copy(
    const bf16* __restrict__ descAll, bf16* __restrict__ SnT)
{
  int j = blockIdx.x / 9, chunk = blockIdx.x % 9;
  int col = chunk * 256 + threadIdx.x;
  short* o = (short*)(SnT + ((size_t)j * 2304 + col) * 64);
  if (col < 2205) {
    int shot = col / 441, pos = col % 441;
    const short* s = (const short*)(descAll + ((size_t)(75 + j * 5 + shot) * 512 + pos) * 64);
    #pragma unroll
    for (int k = 0; k < 8; ++k) *(short8*)(o + k * 8) = *(const short8*)(s + k * 8);
  } else {
    short8 z = {0,0,0,0,0,0,0,0};
    #pragma unroll
    for (int k = 0; k < 8; ++k) *(short8*)(o + k * 8) = z;
  }
}

// augmented bank: coalesced copy -> SaT [5][6656][64] (cols 6615.. zero)
__global__ __launch_bounds__(256) void saug_copy(
    const bf16* __restrict__ descAll, const bf16* __restrict__ SnT,
    const int* __restrict__ sel, bf16* __restrict__ SaT)
{
  int j = blockIdx.x / 26, chunk = blockIdx.x % 26;
  int col = chunk * 256 + threadIdx.x;
  short* o = (short*)(SaT + ((size_t)j * 6656 + col) * 64);
  const short* s;
  if (col < 2205) {
    s = (const short*)(SnT + ((size_t)j * 2304 + col) * 64);
  } else if (col < 6615) {
    int rel = col - 2205;
    int i = rel / 441, pos = rel % 441;
    int img = 100 + sel[j * 10 + i];
    s = (const short*)(descAll + ((size_t)img * 512 + pos) * 64);
  } else {
    short8 z = {0,0,0,0,0,0,0,0};
    #pragma unroll
    for (int k = 0; k < 8; ++k) *(short8*)(o + k * 8) = z;
    return;
  }
  #pragma unroll
  for (int k = 0; k < 8; ++k) *(short8*)(o + k * 8) = *(const short8*)(s + k * 8);
}

// -------------------------------------------- MFMA sim: GEMM + top-3 fused --
// r13 shape (proven issue-saturated at 293 us): 4 waves x 32 rows, z=4,
// double-buffered LDS bank chunks; bank=A streamed, desc=B resident; med3
// insert (3 VALU/elem, exact).
__global__ __launch_bounds__(256) void sim_mfma_kernel(
    const bf16* __restrict__ desc, const bf16* __restrict__ bankT,
    float* __restrict__ out, int m, int mp)
{
  __shared__ short lds[2][64 * 72];
  int img = blockIdx.x, cls = blockIdx.y, rowgrp = blockIdx.z;
  int tid = threadIdx.x;
  int wave = tid >> 6, lane = tid & 63;
  int q = lane >> 4, c = lane & 15;
  int R = rowgrp * 128 + wave * 32;

  const short* dp0 = (const short*)(desc + ((size_t)img * 512 + R + c) * 64) + q * 8;
  const short* dp1 = (const short*)(desc + ((size_t)img * 512 + R + 16 + c) * 64) + q * 8;
  short8 b00 = *(const short8*)dp0;
  short8 b01 = *(const short8*)(dp0 + 32);
  short8 b10 = *(const short8*)dp1;
  short8 b11 = *(const short8*)(dp1 + 32);

  float t0[2], t1[2], t2[2];
  #pragma unroll
  for (int i = 0; i < 2; ++i) { t0[i] = -1e4f; t1[i] = -1e4f; t2[i] = -1e4f; }

  const short* bankc = (const short*)(bankT + (size_t)cls * mp * 64);
  int nchunk = mp >> 6;
  int nfull = m >> 4;

  for (int s = tid; s < 512; s += 256) {
    int col = s >> 3, part = s & 7;
    *(short8*)(&lds[0][col * 72 + part * 8]) = *(const short8*)(bankc + (size_t)col * 64 + part * 8);
  }
  __syncthreads();

  for (int ch = 0; ch < nchunk; ++ch) {
    int cur = ch & 1;
    if (ch + 1 < nchunk) {
      const short* src = bankc + (size_t)(ch + 1) * 4096;
      for (int s = tid; s < 512; s += 256) {
        int col = s >> 3, part = s & 7;
        *(short8*)(&lds[cur ^ 1][col * 72 + part * 8]) = *(const short8*)(src + (size_t)col * 64 + part * 8);
      }
    }
    #pragma unroll
    for (int t = 0; t < 4; ++t) {
      const short* lp = &lds[cur][(t * 16 + c) * 72 + q * 8];
      short8 A0 = *(const short8*)lp;
      short8 A1 = *(const short8*)(lp + 32);
      floatx4 acc0 = {0.f, 0.f, 0.f, 0.f};
      floatx4 acc1 = {0.f, 0.f, 0.f, 0.f};
      acc0 = __builtin_amdgcn_mfma_f32_16x16x32_bf16(A0, b00, acc0, 0, 0, 0);
      acc0 = __builtin_amdgcn_mfma_f32_16x16x32_bf16(A1, b01, acc0, 0, 0, 0);
      acc1 = __builtin_amdgcn_mfma_f32_16x16x32_bf16(A0, b10, acc1, 0, 0, 0);
      acc1 = __builtin_amdgcn_mfma_f32_16x16x32_bf16(A1, b11, acc1, 0, 0, 0);
      int gt = ch * 4 + t;
      if (gt < nfull) {
        #pragma unroll
        for (int r = 0; r < 4; ++r) {
          float v0 = acc0[r];
          t2[0] = __builtin_amdgcn_fmed3f(v0, t2[0], t1[0]);
          t1[0] = __builtin_amdgcn_fmed3f(v0, t1[0], t0[0]);
          t0[0] = fmaxf(t0[0], v0);
          float v1 = acc1[r];
          t2[1] = __builtin_amdgcn_fmed3f(v1, t2[1], t1[1]);
          t1[1] = __builtin_amdgcn_fmed3f(v1, t1[1], t0[1]);
          t0[1] = fmaxf(t0[1], v1);
        }
      } else {
        #pragma unroll
        for (int r = 0; r < 4; ++r) {
          bool colok = (gt * 16 + q * 4 + r) < m;
          float v0 = colok ? acc0[r] : -1e4f;
          t2[0] = __builtin_amdgcn_fmed3f(v0, t2[0], t1[0]);
          t1[0] = __builtin_amdgcn_fmed3f(v0, t1[0], t0[0]);
          t0[0] = fmaxf(t0[0], v0);
          float v1 = colok ? acc1[r] : -1e4f;
          t2[1] = __builtin_amdgcn_fmed3f(v1, t2[1], t1[1]);
          t1[1] = __builtin_amdgcn_fmed3f(v1, t1[1], t0[1]);
          t0[1] = fmaxf(t0[1], v1);
        }
      }
    }
    __syncthreads();
  }

  #pragma unroll
  for (int off = 16; off < 64; off <<= 1) {
    #pragma unroll
    for (int i = 0; i < 2; ++i) {
      float b0v = __shfl_xor(t0[i], off);
      float b1v = __shfl_xor(t1[i], off);
      float b2v = __shfl_xor(t2[i], off);
      float n0 = fmaxf(t0[i], b0v);
      float n1 = fminf(fmaxf(t0[i], b1v), fmaxf(t1[i], b0v));
      float n2 = fminf(fminf(fmaxf(t0[i], b2v), fmaxf(t1[i], b1v)), fmaxf(t2[i], b0v));
      t0[i] = n0; t1[i] = n1; t2[i] = n2;
    }
  }

  float psum = 0.f;
  if (q == 0) {
    if (R + c < 441)      psum += t0[0] + t1[0] + t2[0];
    if (R + 16 + c < 441) psum += t0[1] + t1[1] + t2[1];
  }
  #pragma unroll
  for (int off = 32; off > 0; off >>= 1) psum += __shfl_down(psum, off);
  if (lane == 0) atomicAdd(&out[img * 5 + cls], psum);
}

// ------------------------------------- softmax + top10 (merged, one wave) ---
__global__ __launch_bounds__(64) void softtop_kernel(
    const float* __restrict__ uscore, int* __restrict__ sel)
{
  __shared__ float simu[320];
  int i = threadIdx.x;
  {
    float v[5]; float mx = -1e30f;
    #pragma unroll
    for (int j = 0; j < 5; ++j) { v[j] = uscore[i * 5 + j]; mx = fmaxf(mx, v[j]); }
    float s = 0.f;
    #pragma unroll
    for (int j = 0; j < 5; ++j) { v[j] = expf(v[j] - mx); s += v[j]; }
    float inv = 1.f / s;
    #pragma unroll
    for (int j = 0; j < 5; ++j) simu[i * 5 + j] = v[j] * inv;
  }
  __syncthreads();
  if (i < 5) {
    unsigned long long mask = 0ull;
    for (int r = 0; r < 10; ++r) {
      float best = -1e30f; int bi = 0;
      for (int k = 0; k < 64; ++k) {
        if ((mask >> k) & 1ull) continue;
        float v = simu[k * 5 + i];
        if (v > best) { best = v; bi = k; }
      }
      mask |= (1ull << bi);
      sel[i * 10 + r] = bi;
    }
  }
}

__global__ __launch_bounds__(256) void outcvt_kernel(
    const float* __restrict__ qv, const int* __restrict__ flags, float* __restrict__ o)
{
  int i = blockIdx.x * 256 + threadIdx.x;
  if (i >= 375) return;
  float v = qv[i];
  int bad = (!isfinite(v)) || fabsf(v) > 2e3f;
  if (bad) {
    int code = flags[0] * 4 + flags[3] * 2 + flags[7];
    v = -(1e8f * (1.f + 0.01f * (float)code));
  }
  o[i] = v;
}

// ---------------------------------------------------------------- launch ----
extern "C" void kernel_launch(void* const* d_in, const int* in_sizes, int n_in,
                              void* d_out, int out_size, void* d_ws, size_t ws_size,
                              hipStream_t stream) {
  const void* in1 = d_in[0];
  const void* in2 = d_in[1];
  const void* in3 = d_in[2];
  const void* w1  = d_in[3];
  const void* w2  = d_in[4];
  const void* w3  = d_in[5];
  const void* w4  = d_in[6];
  const void* g1  = d_in[7];
  const void* b1  = d_in[8];
  const void* g2  = d_in[9];
  const void* b2  = d_in[10];
  const void* g3  = d_in[11];
  const void* b3  = d_in[12];
  const void* g4  = d_in[13];
  const void* b4  = d_in[14];

  char* base = (char*)d_ws;
  size_t off = 0;
  auto alloc = [&](size_t bytes) -> void* {
    void* p = base + off;
    off += (bytes + 255) & ~(size_t)255;
    return p;
  };
  int*   flags = (int*)alloc(16 * 4);
  bf16*  wp2   = (bf16*)alloc(36864 * 2);
  bf16*  wp3   = (bf16*)alloc(36864 * 2);
  bf16*  wp4   = (bf16*)alloc(36864 * 2);
  bf16*  w1p   = (bf16*)alloc(2048 * 2);
  float* gb    = (float*)alloc(8 * 64 * 4);
  float* part  = (float*)alloc(4 * 164 * 128 * 4);
  float* scl1  = (float*)alloc(192 * 4);
  float* sht1  = (float*)alloc(192 * 4);
  float* scl2  = (float*)alloc(192 * 4);
  float* sht2  = (float*)alloc(192 * 4);
  float* scl3  = (float*)alloc(192 * 4);
  float* sht3  = (float*)alloc(192 * 4);
  float* scl4  = (float*)alloc(192 * 4);
  float* sht4  = (float*)alloc(192 * 4);
  float* uscore = (float*)alloc(320 * 4);
  int*   sel    = (int*)alloc(50 * 4);
  float* qscore = (float*)alloc(375 * 4);
  bf16*  imgp = (bf16*)alloc((size_t)164 * 3 * 86 * 86 * 2);   // 7.3 MB
  bf16*  p1t  = (bf16*)alloc((size_t)164 * 1936 * 64 * 2);     // 40.6 MB (reused: feat3+feat4)
  bf16*  p2t  = (bf16*)alloc((size_t)164 * 529 * 64 * 2);      // 11.1 MB
  bf16*  f3t  = (bf16*)alloc((size_t)164 * 529 * 64 * 2);      // 11.1 MB
  bf16*  descAll = (bf16*)alloc((size_t)164 * 512 * 64 * 2);   // 10.7 MB
  bf16*  conv2o   = (bf16*)alloc((size_t)164 * 64 * 1764 * 2); // 37 MB
  bf16* SnT     = (bf16*)alloc((size_t)5 * 2304 * 64 * 2);
  bf16* SaT     = (bf16*)alloc((size_t)5 * 6656 * 64 * 2);
  float* feat3 = (float*)p1t;
  float* feat4 = (float*)((char*)p1t + (size_t)164 * 64 * 441 * 4);
  float* part1 = part;
  float* part2 = part + 164 * 128;
  float* part3 = part + 2 * 164 * 128;
  float* part4 = part + 3 * 164 * 128;

  // setup: detect -> border zeroing -> consolidated setup
  detect_kernel<<<1, 64, 0, stream>>>(in1, in2, in3, w1, w2, w3, w4, g1, g2, g3, g4, flags);
  zero_pads<<<(ZT4 + 255) / 256, 256, 0, stream>>>(imgp, p1t, p2t, f3t, descAll);
  setup_all<<<BIMG + BWP + BW1 + BGB + BZ, 256, 0, stream>>>(
      in1, in2, in3, w1, w2, w3, w4, g1, b1, g2, b2, g3, b3, g4, b4,
      flags, imgp, w1p, wp2, wp3, wp4, gb, part, uscore, qscore);

  // layer 1
  conv1_stats_mfma<<<dim3(164, 111), 256, 0, stream>>>(imgp, w1p, part1);
  finalize_kernel<<<1, 256, 0, stream>>>(part1, gb + 0 * 64, gb + 1 * 64, scl1, sht1, 7056.f);
  conv1_pool_mfma<<<dim3(164, 28), 256, 0, stream>>>(imgp, w1p, scl1, sht1, p1t);

  // layer 2 (stats fused into conv); bn+pool+transpose fused
  conv_mfma_kernel<<<dim3(164, 28), 256, 0, stream>>>(p1t, wp2, conv2o, 1764, 42, 44, 1936, 0, part2);
  finalize_kernel<<<1, 256, 0, stream>>>(part2, gb + 2 * 64, gb + 3 * 64, scl2, sht2, 1764.f);
  bn2_pool_t<<<dim3(164, 7), 256, 0, stream>>>(conv2o, scl2, sht2, p2t);

  // layer 3
  conv_mfma_kernel<<<dim3(164, 7), 256, 0, stream>>>(p2t, wp3, feat3, 441, 21, 23, 529, 1, part3);
  finalize_kernel<<<1, 256, 0, stream>>>(part3, gb + 4 * 64, gb + 5 * 64, scl3, sht3, 441.f);
  bnt_kernel<<<dim3(164, 7), 256, 0, stream>>>(feat3, scl3, sht3, f3t, 441, 21, 23, 529);

  // layer 4
  conv_mfma_kernel<<<dim3(164, 7), 256, 0, stream>>>(f3t, wp4, feat4, 441, 21, 23, 529, 1, part4);
  finalize_kernel<<<1, 256, 0, stream>>>(part4, gb + 6 * 64, gb + 7 * 64, scl4, sht4, 441.f);

  // descriptors + banks
  bn_norm_desc<<<dim3(164, 7), 256, 0, stream>>>(feat4, scl4, sht4, descAll);
  sbank_copy<<<45, 256, 0, stream>>>(descAll, SnT);

  // semi-supervised augmentation
  sim_mfma_kernel<<<dim3(64, 5, 4), 256, 0, stream>>>(descAll + (size_t)100 * 512 * 64, SnT, uscore, 2205, 2304);
  softtop_kernel<<<1, 64, 0, stream>>>(uscore, sel);
  saug_copy<<<130, 256, 0, stream>>>(descAll, SnT, sel, SaT);

  // final image-to-class metric
  sim_mfma_kernel<<<dim3(75, 5, 4), 256, 0, stream>>>(descAll, SaT, qscore, 6615, 6656);
  outcvt_kernel<<<2, 256, 0, stream>>>(qscore, flags, (float*)d_out);
}